// Round 2
// baseline (6323.169 us; speedup 1.0000x reference)
//
#include <hip/hip_runtime.h>
#include <hip/hip_bf16.h>
#include <hip/hip_cooperative_groups.h>
#include <stdint.h>

namespace cg = cooperative_groups;

// TemporalDecoder: 2-layer LSTM (H=256) encoder (S=64) + decoder (10 steps) + heads.
// Persistent cooperative kernel: weight-stationary (B tiles in VGPRs), A-frags
// loaded直接 from global, grid.sync() between pipeline rounds.

#define H 256
#define SS 64
#define NN 100
#define BNROWS 1600     // B*N = 16*100
#define KD 512          // concat(x|h) K for cells
#define STEPS 10

typedef __bf16 bf16_t;
typedef __attribute__((ext_vector_type(8))) __bf16 bf16x8;
typedef __attribute__((ext_vector_type(4))) float f32x4;

__device__ __forceinline__ float sigm(float x) { return 1.0f / (1.0f + __expf(-x)); }
__device__ __forceinline__ float tanh_c(float x) {
    x = fminf(fmaxf(x, -15.0f), 15.0f);
    float e = __expf(2.0f * x);
    return (e - 1.0f) / (e + 1.0f);
}

// ---------------------------------------------------------------------------
// prep: pack weights to bf16. Cell weights: new row nr = 4*j + gate, cols
// [W_ih | W_hh] (K=512). bias = b_ih + b_hh. Head layer-1 stacked 512x256.
// ---------------------------------------------------------------------------
__global__ __launch_bounds__(256)
void prep_kernel(const float* __restrict__ Wih0, const float* __restrict__ Whh0,
                 const float* __restrict__ bih0, const float* __restrict__ bhh0,
                 const float* __restrict__ Wih1, const float* __restrict__ Whh1,
                 const float* __restrict__ bih1, const float* __restrict__ bhh1,
                 const float* __restrict__ cw1, const float* __restrict__ sw1,
                 const float* __restrict__ lw1,
                 const float* __restrict__ cb1, const float* __restrict__ sb1,
                 const float* __restrict__ lb1,
                 bf16_t* __restrict__ W0c, bf16_t* __restrict__ W1c,
                 bf16_t* __restrict__ Wh1, float* __restrict__ bias0,
                 float* __restrict__ bias1, float* __restrict__ biash)
{
    int idx = blockIdx.x * 256 + threadIdx.x;
    if (idx < 524288) {
        int nr = idx >> 9, k = idx & 511;
        int j = nr >> 2, gi = nr & 3;
        int go = gi * 256 + j;
        float v = (k < 256) ? Wih0[go * 256 + k] : Whh0[go * 256 + (k - 256)];
        W0c[idx] = (bf16_t)v;
        return;
    }
    idx -= 524288;
    if (idx < 524288) {
        int nr = idx >> 9, k = idx & 511;
        int j = nr >> 2, gi = nr & 3;
        int go = gi * 256 + j;
        float v = (k < 256) ? Wih1[go * 256 + k] : Whh1[go * 256 + (k - 256)];
        W1c[idx] = (bf16_t)v;
        return;
    }
    idx -= 524288;
    if (idx < 131072) {
        int r = idx >> 8, k = idx & 255;
        float v = (r < 128) ? cw1[r * 256 + k]
                            : (r < 256 ? sw1[(r - 128) * 256 + k]
                                       : lw1[(r - 256) * 256 + k]);
        Wh1[idx] = (bf16_t)v;
        return;
    }
    idx -= 131072;
    if (idx < 1024) {
        int j = idx >> 2, gi = idx & 3, go = gi * 256 + j;
        bias0[idx] = bih0[go] + bhh0[go];
        return;
    }
    idx -= 1024;
    if (idx < 1024) {
        int j = idx >> 2, gi = idx & 3, go = gi * 256 + j;
        bias1[idx] = bih1[go] + bhh1[go];
        return;
    }
    idx -= 1024;
    if (idx < 512) {
        biash[idx] = (idx < 128) ? cb1[idx]
                                 : (idx < 256 ? sb1[idx - 128] : lb1[idx - 256]);
    }
}

// ---------------------------------------------------------------------------
// Persistent cooperative kernel.
// 400 blocks x 256 threads, 2 blocks/CU. Blocks 0..199: layer0 cell (tiles
// 64m x 128 gate-cols, mt=cb>>3, nt=cb&7); blocks 200..399: layer1 cell.
// Wave = 64m x 32 gate-cols; B tile (2 nf x 16 kf bf16x8 = 128 VGPR) resident.
// Encoder pipelined: round r runs L0(step r) || L1(step r-1), 65 rounds.
// Decoder: D1 = L0-cell || heads1, D2 = L1-cell || heads2, D3 = LN.
// ---------------------------------------------------------------------------
struct PA {
    const float* x;
    const bf16_t* W0c; const bf16_t* W1c; const bf16_t* Wh1;
    const float* bias0; const float* bias1; const float* biash;
    const float* lng; const float* lnb;
    const float* cw2; const float* cb2;
    const float* sw2; const float* sb2;
    const float* lw2; const float* lb2;
    bf16_t* h0a; bf16_t* h0b; bf16_t* h1a; bf16_t* h1b;
    float* c0; float* c1;
    bf16_t* ht; bf16_t* hid;
    float* out;
};

__global__ __launch_bounds__(256, 2)
void persistent_kernel(PA p)
{
    __shared__ float Gs[4][64 * 36];   // wave-private gate scratch, 36 KB
    cg::grid_group grid = cg::this_grid();

    const int tid  = threadIdx.x;
    const int w    = tid >> 6;
    const int lane = tid & 63;
    const int quad = lane >> 4;
    const int l16  = lane & 15;
    const bool isL0 = (blockIdx.x < 200);
    const int cb   = isL0 ? (int)blockIdx.x : (int)blockIdx.x - 200;
    const int mt   = cb >> 3;          // 0..24
    const int nt   = cb & 7;           // 0..7
    const int mbase = mt * 64;
    const int nbase = nt * 128 + w * 32;   // gate-col base for this wave
    const int hcb   = nbase >> 2;          // h-col base (8 cols per wave)
    float* Gw = &Gs[w][0];

    bf16_t* h0buf[2] = { p.h0a, p.h0b };
    bf16_t* h1buf[2] = { p.h1a, p.h1b };

    int hoffq[4], xoffq[4];
    #pragma unroll
    for (int mf = 0; mf < 4; ++mf) {
        int gm = mbase + mf * 16 + l16;
        hoffq[mf] = gm * 256 + quad * 8;
        int b = gm / 100, n = gm - b * 100;
        xoffq[mf] = (b * 6400 + n) * 256 + quad * 8;
    }

    float bv[2];
    {
        const float* br = isL0 ? p.bias0 : p.bias1;
        #pragma unroll
        for (int nf = 0; nf < 2; ++nf) bv[nf] = br[nbase + nf * 16 + l16];
    }
    const int hb1 = nt * 64 + w * 16;          // heads1 col base (L1 blocks)
    const float bh = p.biash[hb1 + l16];
    float lgv[4], lbv[4];
    #pragma unroll
    for (int j = 0; j < 4; ++j) { lgv[j] = p.lng[lane * 4 + j]; lbv[j] = p.lnb[lane * 4 + j]; }

    // resident B tile: 2 nf x 16 kf bf16x8 = 128 VGPRs
    const bf16_t* Wc = isL0 ? p.W0c : p.W1c;
    bf16x8 Breg[2][16];
    #pragma unroll
    for (int nf = 0; nf < 2; ++nf)
        #pragma unroll
        for (int kf = 0; kf < 16; ++kf)
            Breg[nf][kf] = *(const bf16x8*)(Wc + (size_t)(nbase + nf * 16 + l16) * KD
                                            + kf * 32 + quad * 8);

    float* cst = isL0 ? p.c0 : p.c1;

    // ---- one LSTM cell step for this wave ----
    auto cellw = [&](const float* xsr, int tadd, const bf16_t* s1,
                     const bf16_t* s2, bf16_t* hd) {
        f32x4 zero4 = {0.f, 0.f, 0.f, 0.f};
        f32x4 acc[4][2];
        #pragma unroll
        for (int mf = 0; mf < 4; ++mf)
            #pragma unroll
            for (int nf = 0; nf < 2; ++nf) acc[mf][nf] = zero4;

        #pragma unroll
        for (int kf = 0; kf < 16; ++kf) {
            bf16x8 af[4];
            if (kf < 8) {
                if (xsr) {
                    #pragma unroll
                    for (int mf = 0; mf < 4; ++mf) {
                        const float* pp = xsr + xoffq[mf] + tadd + kf * 32;
                        f32x4 f0 = *(const f32x4*)pp;
                        f32x4 f1 = *(const f32x4*)(pp + 4);
                        bf16x8 v;
                        v[0]=(bf16_t)f0.x; v[1]=(bf16_t)f0.y; v[2]=(bf16_t)f0.z; v[3]=(bf16_t)f0.w;
                        v[4]=(bf16_t)f1.x; v[5]=(bf16_t)f1.y; v[6]=(bf16_t)f1.z; v[7]=(bf16_t)f1.w;
                        af[mf] = v;
                    }
                } else {
                    #pragma unroll
                    for (int mf = 0; mf < 4; ++mf)
                        af[mf] = *(const bf16x8*)(s1 + hoffq[mf] + kf * 32);
                }
            } else {
                #pragma unroll
                for (int mf = 0; mf < 4; ++mf)
                    af[mf] = *(const bf16x8*)(s2 + hoffq[mf] + (kf - 8) * 32);
            }
            #pragma unroll
            for (int mf = 0; mf < 4; ++mf)
                #pragma unroll
                for (int nf = 0; nf < 2; ++nf)
                    acc[mf][nf] = __builtin_amdgcn_mfma_f32_16x16x32_bf16(
                        af[mf], Breg[nf][kf], acc[mf][nf], 0, 0, 0);
        }

        // gates -> wave-private LDS (stride 36: 2-way banks = free)
        #pragma unroll
        for (int mf = 0; mf < 4; ++mf)
            #pragma unroll
            for (int nf = 0; nf < 2; ++nf)
                #pragma unroll
                for (int r = 0; r < 4; ++r)
                    Gw[(mf * 16 + quad * 4 + r) * 36 + nf * 16 + l16] =
                        acc[mf][nf][r] + bv[nf];
        __asm__ volatile("s_waitcnt lgkmcnt(0)" ::: "memory");

        // cell update: 64 m x 8 h-cols per wave, 8 per lane
        #pragma unroll
        for (int e = 0; e < 8; ++e) {
            int id = lane + 64 * e;
            int ml = id >> 3, jl = id & 7;
            f32x4 g4 = *(const f32x4*)(Gw + ml * 36 + jl * 4);   // i,f,g,o
            size_t ci = (size_t)(mbase + ml) * H + hcb + jl;
            float co = cst[ci];
            float iv = sigm(g4.x), fv = sigm(g4.y);
            float gv = tanh_c(g4.z), ov = sigm(g4.w);
            float cn = fv * co + iv * gv;
            cst[ci] = cn;
            hd[ci] = (bf16_t)(ov * tanh_c(cn));
        }
    };

    // ---- heads layer 1 (L1 blocks): hid = relu(ht @ Wh1^T + bh) ----
    auto heads1w = [&]() {
        f32x4 zero4 = {0.f, 0.f, 0.f, 0.f};
        f32x4 ha[4] = {zero4, zero4, zero4, zero4};
        #pragma unroll
        for (int kf = 0; kf < 8; ++kf) {
            bf16x8 af[4];
            #pragma unroll
            for (int mf = 0; mf < 4; ++mf)
                af[mf] = *(const bf16x8*)(p.ht + hoffq[mf] + kf * 32);
            bf16x8 bb = *(const bf16x8*)(p.Wh1 + (size_t)(hb1 + l16) * H
                                         + kf * 32 + quad * 8);
            #pragma unroll
            for (int mf = 0; mf < 4; ++mf)
                ha[mf] = __builtin_amdgcn_mfma_f32_16x16x32_bf16(af[mf], bb, ha[mf], 0, 0, 0);
        }
        #pragma unroll
        for (int mf = 0; mf < 4; ++mf)
            #pragma unroll
            for (int r = 0; r < 4; ++r) {
                int mg = mbase + mf * 16 + quad * 4 + r;
                int ng = hb1 + l16;
                float v = ha[mf][r] + bh;
                p.hid[(size_t)mg * 512 + ng] = (bf16_t)fmaxf(v, 0.0f);
            }
    };

    // ---- heads layer 2 (L0 blocks): block-diagonal tiny GEMV -> out ----
    auto heads2w = [&](int s) {
        int idx = cb * 256 + tid;
        if (idx >= BNROWS * 22) return;
        int m = idx / 22;
        int o = idx - m * 22;
        const bf16_t* hrow = p.hid + (size_t)m * 512;
        const float* wp; float bias; int k0, len;
        if (o < 4)      { wp = p.cw2 + o * 128;       bias = p.cb2[o];     k0 = 0;   len = 128; }
        else if (o < 6) { wp = p.sw2 + (o - 4) * 128; bias = p.sb2[o - 4]; k0 = 128; len = 128; }
        else            { wp = p.lw2 + (o - 6) * 256; bias = p.lb2[o - 6]; k0 = 256; len = 256; }
        float acc = bias;
        for (int k = 0; k < len; k += 4) {
            f32x4 wv = *(const f32x4*)(wp + k);
            acc += (float)hrow[k0 + k]     * wv.x;
            acc += (float)hrow[k0 + k + 1] * wv.y;
            acc += (float)hrow[k0 + k + 2] * wv.z;
            acc += (float)hrow[k0 + k + 3] * wv.w;
        }
        int b = m / NN, n = m - b * NN;
        p.out[(((size_t)b * STEPS + s) * NN + n) * 22 + o] = acc;
    };

    // ---- layernorm (all 400 blocks, 4 samples each) ----
    auto lnw = [&](const bf16_t* src) {
        int sample = blockIdx.x * 4 + w;
        const bf16_t* rw2 = src + (size_t)sample * H;
        float v[4];
        #pragma unroll
        for (int j = 0; j < 4; ++j) v[j] = (float)rw2[lane * 4 + j];
        float sm = v[0] + v[1] + v[2] + v[3];
        #pragma unroll
        for (int off = 32; off > 0; off >>= 1) sm += __shfl_xor(sm, off);
        float mean = sm * (1.0f / H);
        float q = 0.f;
        #pragma unroll
        for (int j = 0; j < 4; ++j) { float d = v[j] - mean; q += d * d; }
        #pragma unroll
        for (int off = 32; off > 0; off >>= 1) q += __shfl_xor(q, off);
        float rstd = rsqrtf(q * (1.0f / H) + 1e-5f);
        #pragma unroll
        for (int j = 0; j < 4; ++j)
            p.ht[(size_t)sample * H + lane * 4 + j] =
                (bf16_t)((v[j] - mean) * rstd * lgv[j] + lbv[j]);
    };

    // ======== encoder: 65 pipelined rounds ========
    #pragma unroll 1
    for (int r = 0; r < 65; ++r) {
        if (isL0) {
            if (r < 64)
                cellw(p.x, r * 25600, nullptr, h0buf[(r + 1) & 1], h0buf[r & 1]);
        } else {
            if (r >= 1)
                cellw(nullptr, 0, h0buf[(r + 1) & 1], h1buf[r & 1], h1buf[(r + 1) & 1]);
        }
        grid.sync();
    }
    // h1(63) in h1buf[1], h0(63) in h0buf[1]
    lnw(h1buf[1]);
    grid.sync();

    // ======== decoder: 10 steps ========
    #pragma unroll 1
    for (int s = 0; s < STEPS; ++s) {
        if (isL0) cellw(nullptr, 0, p.ht, h0buf[(s + 1) & 1], h0buf[s & 1]);
        else      heads1w();
        grid.sync();
        if (!isL0) cellw(nullptr, 0, h0buf[s & 1], h1buf[(s + 1) & 1], h1buf[s & 1]);
        else       heads2w(s);
        grid.sync();
        if (s < STEPS - 1) { lnw(h1buf[s & 1]); grid.sync(); }
    }
}

// ===========================================================================
// Fallback path (round-1 kernels, used only if cooperative launch fails)
// ===========================================================================
__global__ __launch_bounds__(256)
void cell_kernel(const float* __restrict__ xsrc, int t,
                 const bf16_t* __restrict__ a1,
                 const bf16_t* __restrict__ a2,
                 const bf16_t* __restrict__ Wc,
                 const float* __restrict__ biasr,
                 float* __restrict__ cst,
                 bf16_t* __restrict__ hout)
{
    __shared__ char smem_raw[18432];
    bf16_t* As = (bf16_t*)smem_raw;
    bf16_t* Bs = (bf16_t*)(smem_raw + 9216);
    float*  Gsf = (float*)smem_raw;

    const int tid  = threadIdx.x;
    const int mblk = blockIdx.x;
    const int nblk = blockIdx.y;
    const int am = tid >> 2;
    const int kc = (tid & 3) << 4;
    const int gm = mblk * 64 + am;

    const float*  xrow  = nullptr;
    const bf16_t* arow1 = nullptr;
    if (xsrc) {
        int b = gm / NN;
        int n = gm - b * NN;
        xrow = xsrc + (((size_t)b * SS + t) * NN + n) * H;
    } else {
        arow1 = a1 + (size_t)gm * H;
    }
    const bf16_t* arow2 = a2 + (size_t)gm * H;
    const bf16_t* brow  = Wc + (size_t)(nblk * 64 + am) * KD;

    bf16x8 ra0, ra1, rb0, rb1;
    auto loadA = [&](int ko) {
        int k = ko + kc;
        if (xsrc) {
            if (k < 256) {
                const f32x4* pq = (const f32x4*)(xrow + k);
                f32x4 f0 = pq[0], f1 = pq[1], f2 = pq[2], f3 = pq[3];
                bf16x8 v0, v1;
                v0[0]=(bf16_t)f0.x; v0[1]=(bf16_t)f0.y; v0[2]=(bf16_t)f0.z; v0[3]=(bf16_t)f0.w;
                v0[4]=(bf16_t)f1.x; v0[5]=(bf16_t)f1.y; v0[6]=(bf16_t)f1.z; v0[7]=(bf16_t)f1.w;
                v1[0]=(bf16_t)f2.x; v1[1]=(bf16_t)f2.y; v1[2]=(bf16_t)f2.z; v1[3]=(bf16_t)f2.w;
                v1[4]=(bf16_t)f3.x; v1[5]=(bf16_t)f3.y; v1[6]=(bf16_t)f3.z; v1[7]=(bf16_t)f3.w;
                ra0 = v0; ra1 = v1;
            } else {
                const bf16x8* pq = (const bf16x8*)(arow2 + (k - 256));
                ra0 = pq[0]; ra1 = pq[1];
            }
        } else {
            const bf16x8* pq = (k < 256) ? (const bf16x8*)(arow1 + k)
                                         : (const bf16x8*)(arow2 + (k - 256));
            ra0 = pq[0]; ra1 = pq[1];
        }
    };
    auto loadB = [&](int ko) {
        const bf16x8* pq = (const bf16x8*)(brow + ko + kc);
        rb0 = pq[0]; rb1 = pq[1];
    };
    loadA(0); loadB(0);

    const int w    = tid >> 6;
    const int lane = tid & 63;
    const int wm   = w & 1, wn = w >> 1;
    const int quad = lane >> 4, l16 = lane & 15;

    f32x4 zero4 = {0.f, 0.f, 0.f, 0.f};
    f32x4 acc[2][2] = {{zero4, zero4}, {zero4, zero4}};

    for (int kk = 0; kk < 8; ++kk) {
        __syncthreads();
        *(bf16x8*)(As + am * 72 + kc)     = ra0;
        *(bf16x8*)(As + am * 72 + kc + 8) = ra1;
        *(bf16x8*)(Bs + am * 72 + kc)     = rb0;
        *(bf16x8*)(Bs + am * 72 + kc + 8) = rb1;
        __syncthreads();
        if (kk < 7) { loadA((kk + 1) * 64); loadB((kk + 1) * 64); }
        #pragma unroll
        for (int ks = 0; ks < 2; ++ks) {
            bf16x8 af[2], bb[2];
            #pragma unroll
            for (int mi = 0; mi < 2; ++mi)
                af[mi] = *(const bf16x8*)(As + (wm * 32 + mi * 16 + l16) * 72 + ks * 32 + quad * 8);
            #pragma unroll
            for (int ni = 0; ni < 2; ++ni)
                bb[ni] = *(const bf16x8*)(Bs + (wn * 32 + ni * 16 + l16) * 72 + ks * 32 + quad * 8);
            #pragma unroll
            for (int mi = 0; mi < 2; ++mi)
                #pragma unroll
                for (int ni = 0; ni < 2; ++ni)
                    acc[mi][ni] = __builtin_amdgcn_mfma_f32_16x16x32_bf16(
                        af[mi], bb[ni], acc[mi][ni], 0, 0, 0);
        }
    }

    __syncthreads();
    float bvv[2];
    #pragma unroll
    for (int ni = 0; ni < 2; ++ni)
        bvv[ni] = biasr[nblk * 64 + wn * 32 + ni * 16 + l16];

    #pragma unroll
    for (int mi = 0; mi < 2; ++mi)
        #pragma unroll
        for (int ni = 0; ni < 2; ++ni)
            #pragma unroll
            for (int r = 0; r < 4; ++r) {
                int ml = wm * 32 + mi * 16 + quad * 4 + r;
                int nl = wn * 32 + ni * 16 + l16;
                Gsf[ml * 68 + nl] = acc[mi][ni][r] + bvv[ni];
            }
    __syncthreads();

    #pragma unroll
    for (int e = 0; e < 4; ++e) {
        int id = tid + 256 * e;
        int ml = id >> 4;
        int jl = id & 15;
        f32x4 g4 = *(const f32x4*)(Gsf + ml * 68 + jl * 4);
        int gmm = mblk * 64 + ml;
        int jg  = nblk * 16 + jl;
        float co = cst[(size_t)gmm * H + jg];
        float iv = sigm(g4.x);
        float fv = sigm(g4.y);
        float gv = tanh_c(g4.z);
        float ov = sigm(g4.w);
        float cn = fv * co + iv * gv;
        float hn = ov * tanh_c(cn);
        cst[(size_t)gmm * H + jg]  = cn;
        hout[(size_t)gmm * H + jg] = (bf16_t)hn;
    }
}

__global__ __launch_bounds__(256)
void heads1_kernel(const bf16_t* __restrict__ a1,
                   const bf16_t* __restrict__ Wh,
                   const float* __restrict__ biash,
                   bf16_t* __restrict__ hid)
{
    __shared__ char smem_raw[18432];
    bf16_t* As = (bf16_t*)smem_raw;
    bf16_t* Bs = (bf16_t*)(smem_raw + 9216);

    const int tid  = threadIdx.x;
    const int mblk = blockIdx.x;
    const int nblk = blockIdx.y;
    const int am = tid >> 2;
    const int kc = (tid & 3) << 4;
    const int gm = mblk * 64 + am;
    const bf16_t* arow = a1 + (size_t)gm * H;
    const bf16_t* brow = Wh + (size_t)(nblk * 64 + am) * H;

    bf16x8 ra0, ra1, rb0, rb1;
    auto load = [&](int ko) {
        const bf16x8* pa = (const bf16x8*)(arow + ko + kc);
        ra0 = pa[0]; ra1 = pa[1];
        const bf16x8* pb = (const bf16x8*)(brow + ko + kc);
        rb0 = pb[0]; rb1 = pb[1];
    };
    load(0);

    const int w    = tid >> 6;
    const int lane = tid & 63;
    const int wm   = w & 1, wn = w >> 1;
    const int quad = lane >> 4, l16 = lane & 15;

    f32x4 zero4 = {0.f, 0.f, 0.f, 0.f};
    f32x4 acc[2][2] = {{zero4, zero4}, {zero4, zero4}};

    for (int kk = 0; kk < 4; ++kk) {
        __syncthreads();
        *(bf16x8*)(As + am * 72 + kc)     = ra0;
        *(bf16x8*)(As + am * 72 + kc + 8) = ra1;
        *(bf16x8*)(Bs + am * 72 + kc)     = rb0;
        *(bf16x8*)(Bs + am * 72 + kc + 8) = rb1;
        __syncthreads();
        if (kk < 3) load((kk + 1) * 64);
        #pragma unroll
        for (int ks = 0; ks < 2; ++ks) {
            bf16x8 af[2], bb[2];
            #pragma unroll
            for (int mi = 0; mi < 2; ++mi)
                af[mi] = *(const bf16x8*)(As + (wm * 32 + mi * 16 + l16) * 72 + ks * 32 + quad * 8);
            #pragma unroll
            for (int ni = 0; ni < 2; ++ni)
                bb[ni] = *(const bf16x8*)(Bs + (wn * 32 + ni * 16 + l16) * 72 + ks * 32 + quad * 8);
            #pragma unroll
            for (int mi = 0; mi < 2; ++mi)
                #pragma unroll
                for (int ni = 0; ni < 2; ++ni)
                    acc[mi][ni] = __builtin_amdgcn_mfma_f32_16x16x32_bf16(
                        af[mi], bb[ni], acc[mi][ni], 0, 0, 0);
        }
    }

    #pragma unroll
    for (int mi = 0; mi < 2; ++mi)
        #pragma unroll
        for (int ni = 0; ni < 2; ++ni)
            #pragma unroll
            for (int r = 0; r < 4; ++r) {
                int mg = mblk * 64 + wm * 32 + mi * 16 + quad * 4 + r;
                int ng = nblk * 64 + wn * 32 + ni * 16 + l16;
                float v = acc[mi][ni][r] + biash[ng];
                hid[(size_t)mg * 512 + ng] = (bf16_t)fmaxf(v, 0.0f);
            }
}

__global__ __launch_bounds__(256)
void heads2_kernel(const bf16_t* __restrict__ hid,
                   const float* __restrict__ cw2, const float* __restrict__ cb2,
                   const float* __restrict__ sw2, const float* __restrict__ sb2,
                   const float* __restrict__ lw2, const float* __restrict__ lb2,
                   float* __restrict__ out, int s)
{
    int idx = blockIdx.x * 256 + threadIdx.x;
    if (idx >= BNROWS * 22) return;
    int m = idx / 22;
    int o = idx - m * 22;
    const bf16_t* hrow = hid + (size_t)m * 512;
    const float* wp; float bias; int k0, len;
    if (o < 4)      { wp = cw2 + o * 128;       bias = cb2[o];     k0 = 0;   len = 128; }
    else if (o < 6) { wp = sw2 + (o - 4) * 128; bias = sb2[o - 4]; k0 = 128; len = 128; }
    else            { wp = lw2 + (o - 6) * 256; bias = lb2[o - 6]; k0 = 256; len = 256; }
    float acc = bias;
    for (int k = 0; k < len; k += 4) {
        f32x4 wv = *(const f32x4*)(wp + k);
        acc += (float)hrow[k0 + k]     * wv.x;
        acc += (float)hrow[k0 + k + 1] * wv.y;
        acc += (float)hrow[k0 + k + 2] * wv.z;
        acc += (float)hrow[k0 + k + 3] * wv.w;
    }
    int b = m / NN, n = m - b * NN;
    out[(((size_t)b * STEPS + s) * NN + n) * 22 + o] = acc;
}

__global__ __launch_bounds__(256)
void ln_kernel(const bf16_t* __restrict__ hin,
               const float* __restrict__ gam, const float* __restrict__ bet,
               bf16_t* __restrict__ hto)
{
    int w = threadIdx.x >> 6;
    int lane = threadIdx.x & 63;
    int sample = blockIdx.x * 4 + w;
    const bf16_t* row = hin + (size_t)sample * H;
    float v[4];
    #pragma unroll
    for (int j = 0; j < 4; ++j) v[j] = (float)row[lane * 4 + j];
    float sm = v[0] + v[1] + v[2] + v[3];
    #pragma unroll
    for (int off = 32; off > 0; off >>= 1) sm += __shfl_xor(sm, off);
    float mean = sm * (1.0f / H);
    float q = 0.f;
    #pragma unroll
    for (int j = 0; j < 4; ++j) { float d = v[j] - mean; q += d * d; }
    #pragma unroll
    for (int off = 32; off > 0; off >>= 1) q += __shfl_xor(q, off);
    float rstd = rsqrtf(q * (1.0f / H) + 1e-5f);
    #pragma unroll
    for (int j = 0; j < 4; ++j) {
        int idx = lane * 4 + j;
        float o = (v[j] - mean) * rstd * gam[idx] + bet[idx];
        hto[(size_t)sample * H + idx] = (bf16_t)o;
    }
}

// ---------------------------------------------------------------------------
extern "C" void kernel_launch(void* const* d_in, const int* in_sizes, int n_in,
                              void* d_out, int out_size, void* d_ws, size_t ws_size,
                              hipStream_t stream)
{
    const float* x    = (const float*)d_in[0];
    const float* Wih0 = (const float*)d_in[1];
    const float* Whh0 = (const float*)d_in[2];
    const float* bih0 = (const float*)d_in[3];
    const float* bhh0 = (const float*)d_in[4];
    const float* Wih1 = (const float*)d_in[5];
    const float* Whh1 = (const float*)d_in[6];
    const float* bih1 = (const float*)d_in[7];
    const float* bhh1 = (const float*)d_in[8];
    const float* lng  = (const float*)d_in[9];
    const float* lnb  = (const float*)d_in[10];
    const float* cw1  = (const float*)d_in[11];
    const float* cb1  = (const float*)d_in[12];
    const float* cw2  = (const float*)d_in[13];
    const float* cb2  = (const float*)d_in[14];
    const float* sw1  = (const float*)d_in[15];
    const float* sb1  = (const float*)d_in[16];
    const float* sw2  = (const float*)d_in[17];
    const float* sb2  = (const float*)d_in[18];
    const float* lw1  = (const float*)d_in[19];
    const float* lb1  = (const float*)d_in[20];
    const float* lw2  = (const float*)d_in[21];
    const float* lb2  = (const float*)d_in[22];
    float* out = (float*)d_out;

    char* ws = (char*)d_ws;
    if (ws_size < 11500000) return;

    bf16_t* W0c   = (bf16_t*)(ws);
    bf16_t* W1c   = (bf16_t*)(ws + 1048576);
    bf16_t* Wh1w  = (bf16_t*)(ws + 2097152);
    float*  bias0 = (float*)(ws + 2359296);
    float*  bias1 = (float*)(ws + 2363392);
    float*  biash = (float*)(ws + 2367488);
    char* st = ws + 2369536;
    bf16_t* h0a = (bf16_t*)st;
    bf16_t* h0b = (bf16_t*)(st + 819200);
    bf16_t* h1a = (bf16_t*)(st + 1638400);
    bf16_t* h1b = (bf16_t*)(st + 2457600);
    float*  c0  = (float*)(st + 3276800);
    float*  c1  = (float*)(st + 4915200);
    bf16_t* ht  = (bf16_t*)(st + 6553600);
    bf16_t* hid = (bf16_t*)(st + 7372800);

    hipMemsetAsync(st, 0, 6553600, stream);

    prep_kernel<<<4615, 256, 0, stream>>>(Wih0, Whh0, bih0, bhh0,
                                          Wih1, Whh1, bih1, bhh1,
                                          cw1, sw1, lw1, cb1, sb1, lb1,
                                          W0c, W1c, Wh1w, bias0, bias1, biash);

    PA pa;
    pa.x = x; pa.W0c = W0c; pa.W1c = W1c; pa.Wh1 = Wh1w;
    pa.bias0 = bias0; pa.bias1 = bias1; pa.biash = biash;
    pa.lng = lng; pa.lnb = lnb;
    pa.cw2 = cw2; pa.cb2 = cb2; pa.sw2 = sw2; pa.sb2 = sb2;
    pa.lw2 = lw2; pa.lb2 = lb2;
    pa.h0a = h0a; pa.h0b = h0b; pa.h1a = h1a; pa.h1b = h1b;
    pa.c0 = c0; pa.c1 = c1; pa.ht = ht; pa.hid = hid; pa.out = out;

    void* kargs[] = { &pa };
    hipError_t err = hipLaunchCooperativeKernel((void*)persistent_kernel,
                                                dim3(400), dim3(256),
                                                kargs, 0, stream);
    if (err == hipSuccess) return;

    // -------- fallback: round-1 multi-launch path --------
    bf16_t* h0buf[2] = { h0a, h0b };
    bf16_t* h1buf[2] = { h1a, h1b };
    dim3 cg2(25, 16);
    int cur = 0;
    for (int t = 0; t < SS; ++t) {
        cell_kernel<<<cg2, 256, 0, stream>>>(x, t, nullptr, h0buf[cur], W0c, bias0,
                                             c0, h0buf[cur ^ 1]);
        cell_kernel<<<cg2, 256, 0, stream>>>(nullptr, 0, h0buf[cur ^ 1], h1buf[cur],
                                             W1c, bias1, c1, h1buf[cur ^ 1]);
        cur ^= 1;
    }
    ln_kernel<<<400, 256, 0, stream>>>(h1buf[cur], lng, lnb, ht);
    for (int s = 0; s < STEPS; ++s) {
        heads1_kernel<<<dim3(25, 8), 256, 0, stream>>>(ht, Wh1w, biash, hid);
        heads2_kernel<<<138, 256, 0, stream>>>(hid, cw2, cb2, sw2, sb2, lw2, lb2,
                                               out, s);
        cell_kernel<<<cg2, 256, 0, stream>>>(nullptr, 0, ht, h0buf[cur], W0c, bias0,
                                             c0, h0buf[cur ^ 1]);
        cell_kernel<<<cg2, 256, 0, stream>>>(nullptr, 0, h0buf[cur ^ 1], h1buf[cur],
                                             W1c, bias1, c1, h1buf[cur ^ 1]);
        cur ^= 1;
        ln_kernel<<<400, 256, 0, stream>>>(h1buf[cur], lng, lnb, ht);
    }
}

// Round 3
// 3872.540 us; speedup vs baseline: 1.6328x; 1.6328x over previous
//
#include <hip/hip_runtime.h>
#include <hip/hip_bf16.h>
#include <stdint.h>

// TemporalDecoder: 2-layer LSTM (H=256) encoder (S=64) + decoder (10 steps) + heads.
// Persistent kernel, weight-stationary (B tiles in VGPRs), c-state in registers.
// All dataflow is local to 16-block groups (8 L0 + 8 L1 blocks sharing one
// 64-row m-tile) -> per-group counter barriers instead of grid.sync().

#define H 256
#define SS 64
#define NN 100
#define BNROWS 1600     // B*N = 16*100
#define KD 512          // concat(x|h) K for cells
#define STEPS 10

typedef __bf16 bf16_t;
typedef __attribute__((ext_vector_type(8))) __bf16 bf16x8;
typedef __attribute__((ext_vector_type(4))) __bf16 bf16x4;
typedef __attribute__((ext_vector_type(4))) float f32x4;

__device__ __forceinline__ float sigm(float x) { return 1.0f / (1.0f + __expf(-x)); }
__device__ __forceinline__ float tanh_c(float x) {
    x = fminf(fmaxf(x, -15.0f), 15.0f);
    float e = __expf(2.0f * x);
    return (e - 1.0f) / (e + 1.0f);
}

// ---------------------------------------------------------------------------
// prep: pack weights to bf16. Cell weights: new row nr = 4*j + gate, cols
// [W_ih | W_hh] (K=512). bias = b_ih + b_hh. Head layer-1 stacked 512x256.
// ---------------------------------------------------------------------------
__global__ __launch_bounds__(256)
void prep_kernel(const float* __restrict__ Wih0, const float* __restrict__ Whh0,
                 const float* __restrict__ bih0, const float* __restrict__ bhh0,
                 const float* __restrict__ Wih1, const float* __restrict__ Whh1,
                 const float* __restrict__ bih1, const float* __restrict__ bhh1,
                 const float* __restrict__ cw1, const float* __restrict__ sw1,
                 const float* __restrict__ lw1,
                 const float* __restrict__ cb1, const float* __restrict__ sb1,
                 const float* __restrict__ lb1,
                 bf16_t* __restrict__ W0c, bf16_t* __restrict__ W1c,
                 bf16_t* __restrict__ Wh1, float* __restrict__ bias0,
                 float* __restrict__ bias1, float* __restrict__ biash)
{
    int idx = blockIdx.x * 256 + threadIdx.x;
    if (idx < 524288) {
        int nr = idx >> 9, k = idx & 511;
        int j = nr >> 2, gi = nr & 3;
        int go = gi * 256 + j;
        float v = (k < 256) ? Wih0[go * 256 + k] : Whh0[go * 256 + (k - 256)];
        W0c[idx] = (bf16_t)v;
        return;
    }
    idx -= 524288;
    if (idx < 524288) {
        int nr = idx >> 9, k = idx & 511;
        int j = nr >> 2, gi = nr & 3;
        int go = gi * 256 + j;
        float v = (k < 256) ? Wih1[go * 256 + k] : Whh1[go * 256 + (k - 256)];
        W1c[idx] = (bf16_t)v;
        return;
    }
    idx -= 524288;
    if (idx < 131072) {
        int r = idx >> 8, k = idx & 255;
        float v = (r < 128) ? cw1[r * 256 + k]
                            : (r < 256 ? sw1[(r - 128) * 256 + k]
                                       : lw1[(r - 256) * 256 + k]);
        Wh1[idx] = (bf16_t)v;
        return;
    }
    idx -= 131072;
    if (idx < 1024) {
        int j = idx >> 2, gi = idx & 3, go = gi * 256 + j;
        bias0[idx] = bih0[go] + bhh0[go];
        return;
    }
    idx -= 1024;
    if (idx < 1024) {
        int j = idx >> 2, gi = idx & 3, go = gi * 256 + j;
        bias1[idx] = bih1[go] + bhh1[go];
        return;
    }
    idx -= 1024;
    if (idx < 512) {
        biash[idx] = (idx < 128) ? cb1[idx]
                                 : (idx < 256 ? sb1[idx - 128] : lb1[idx - 256]);
    }
}

// x fp32 -> bf16 (same element layout), 26,214,400 elements, 4 per thread.
__global__ __launch_bounds__(256)
void xconv_kernel(const float* __restrict__ x, bf16_t* __restrict__ xb)
{
    int i = (blockIdx.x * 256 + threadIdx.x) * 4;
    f32x4 v = *(const f32x4*)(x + i);
    bf16x4 o;
    o[0] = (bf16_t)v.x; o[1] = (bf16_t)v.y; o[2] = (bf16_t)v.z; o[3] = (bf16_t)v.w;
    *(bf16x4*)(xb + i) = o;
}

// ---------------------------------------------------------------------------
// Persistent kernel. 400 blocks x 256 threads (2/CU). Group g = mt in [0,25):
// blocks {L0(mt,nt=0..7), L1(mt,nt=0..7)} own rows [mt*64, mt*64+64). All
// communication is group-internal -> 16-block counter barrier per group.
// Wave = 64m x 32 gate-cols; B tile (2nf x 16kf bf16x8 = 128 VGPR) resident;
// c-state in registers (8 floats/lane, wave-exclusive).
// ---------------------------------------------------------------------------
struct PA {
    const bf16_t* xb;
    const bf16_t* W0c; const bf16_t* W1c; const bf16_t* Wh1;
    const float* bias0; const float* bias1; const float* biash;
    const float* lng; const float* lnb;
    const float* cw2; const float* cb2;
    const float* sw2; const float* sb2;
    const float* lw2; const float* lb2;
    bf16_t* h0a; bf16_t* h0b; bf16_t* h1a; bf16_t* h1b;
    bf16_t* ht; bf16_t* hid;
    unsigned* cnt;          // 25 groups x 64 uints (256 B stride)
    float* out;
};

__global__ __launch_bounds__(256, 2)
void persistent_kernel(PA p)
{
    __shared__ float Gs[4][64 * 36];   // wave-private gate scratch, 36 KB

    const int tid  = threadIdx.x;
    const int w    = tid >> 6;
    const int lane = tid & 63;
    const int quad = lane >> 4;
    const int l16  = lane & 15;
    const bool isL0 = (blockIdx.x < 200);
    const int cb   = isL0 ? (int)blockIdx.x : (int)blockIdx.x - 200;
    const int mt   = cb >> 3;              // group 0..24
    const int nt   = cb & 7;               // 0..7
    const int bg   = nt + (isL0 ? 0 : 8);  // group-local block id 0..15
    const int mbase = mt * 64;
    const int nbase = nt * 128 + w * 32;   // gate-col base for this wave
    const int hcb   = nbase >> 2;          // h-col base (8 cols per wave)
    float* Gw = &Gs[w][0];

    unsigned* cntg = p.cnt + mt * 64;      // group-private line
    unsigned rnd = 0;
    auto bar = [&]() {
        ++rnd;
        __syncthreads();
        if (tid == 0) {
            __threadfence();   // release: drain my XCD-L2 writes
            __hip_atomic_fetch_add(cntg, 1u, __ATOMIC_RELAXED, __HIP_MEMORY_SCOPE_AGENT);
            while (__hip_atomic_load(cntg, __ATOMIC_RELAXED, __HIP_MEMORY_SCOPE_AGENT)
                   < 16u * rnd) { }
            __threadfence();   // acquire: invalidate stale cached lines
        }
        __syncthreads();
    };

    bf16_t* h0buf[2] = { p.h0a, p.h0b };
    bf16_t* h1buf[2] = { p.h1a, p.h1b };

    int hoffq[4], xoffq[4];
    #pragma unroll
    for (int mf = 0; mf < 4; ++mf) {
        int gm = mbase + mf * 16 + l16;
        hoffq[mf] = gm * 256 + quad * 8;
        int b = gm / 100, n = gm - b * 100;
        xoffq[mf] = (b * 6400 + n) * 256 + quad * 8;
    }

    float bv[2];
    {
        const float* br = isL0 ? p.bias0 : p.bias1;
        #pragma unroll
        for (int nf = 0; nf < 2; ++nf) bv[nf] = br[nbase + nf * 16 + l16];
    }
    const int hb1 = nt * 64 + w * 16;          // heads1 col base (L1 blocks)
    const float bh = p.biash[hb1 + l16];
    float lgv[4], lbv[4];
    #pragma unroll
    for (int j = 0; j < 4; ++j) { lgv[j] = p.lng[lane * 4 + j]; lbv[j] = p.lnb[lane * 4 + j]; }

    // resident B tile: 2 nf x 16 kf bf16x8 = 128 VGPRs
    const bf16_t* Wc = isL0 ? p.W0c : p.W1c;
    bf16x8 Breg[2][16];
    #pragma unroll
    for (int nf = 0; nf < 2; ++nf)
        #pragma unroll
        for (int kf = 0; kf < 16; ++kf)
            Breg[nf][kf] = *(const bf16x8*)(Wc + (size_t)(nbase + nf * 16 + l16) * KD
                                            + kf * 32 + quad * 8);

    // c-state: wave-exclusive, 8 floats/lane. e -> (ml = e*8 + lane/8, jl = lane%7+1... )
    float creg[8];
    #pragma unroll
    for (int e = 0; e < 8; ++e) creg[e] = 0.0f;

    // ---- one LSTM cell step for this wave ----
    auto cellw = [&](const bf16_t* s1, const int* off1, const bf16_t* s2,
                     bf16_t* hd) {
        f32x4 zero4 = {0.f, 0.f, 0.f, 0.f};
        f32x4 acc[4][2];
        #pragma unroll
        for (int mf = 0; mf < 4; ++mf)
            #pragma unroll
            for (int nf = 0; nf < 2; ++nf) acc[mf][nf] = zero4;

        #pragma unroll
        for (int kf = 0; kf < 16; ++kf) {
            bf16x8 af[4];
            #pragma unroll
            for (int mf = 0; mf < 4; ++mf)
                af[mf] = (kf < 8)
                    ? *(const bf16x8*)(s1 + off1[mf] + kf * 32)
                    : *(const bf16x8*)(s2 + hoffq[mf] + (kf - 8) * 32);
            #pragma unroll
            for (int mf = 0; mf < 4; ++mf)
                #pragma unroll
                for (int nf = 0; nf < 2; ++nf)
                    acc[mf][nf] = __builtin_amdgcn_mfma_f32_16x16x32_bf16(
                        af[mf], Breg[nf][kf], acc[mf][nf], 0, 0, 0);
        }

        // gates -> wave-private LDS
        #pragma unroll
        for (int mf = 0; mf < 4; ++mf)
            #pragma unroll
            for (int nf = 0; nf < 2; ++nf)
                #pragma unroll
                for (int r = 0; r < 4; ++r)
                    Gw[(mf * 16 + quad * 4 + r) * 36 + nf * 16 + l16] =
                        acc[mf][nf][r] + bv[nf];
        __asm__ volatile("s_waitcnt lgkmcnt(0)" ::: "memory");

        // cell update: 64 m x 8 h-cols per wave, 8 per lane, c in registers
        #pragma unroll
        for (int e = 0; e < 8; ++e) {
            int ml = e * 8 + (lane >> 3);
            int jl = lane & 7;
            f32x4 g4 = *(const f32x4*)(Gw + ml * 36 + jl * 4);   // i,f,g,o
            float iv = sigm(g4.x), fv = sigm(g4.y);
            float gv = tanh_c(g4.z), ov = sigm(g4.w);
            float cn = fv * creg[e] + iv * gv;
            creg[e] = cn;
            hd[(size_t)(mbase + ml) * H + hcb + jl] = (bf16_t)(ov * tanh_c(cn));
        }
    };

    // ---- heads layer 1 (L1 blocks): hid = relu(ht @ Wh1^T + bh) ----
    auto heads1w = [&]() {
        f32x4 zero4 = {0.f, 0.f, 0.f, 0.f};
        f32x4 ha[4] = {zero4, zero4, zero4, zero4};
        #pragma unroll
        for (int kf = 0; kf < 8; ++kf) {
            bf16x8 af[4];
            #pragma unroll
            for (int mf = 0; mf < 4; ++mf)
                af[mf] = *(const bf16x8*)(p.ht + hoffq[mf] + kf * 32);
            bf16x8 bb = *(const bf16x8*)(p.Wh1 + (size_t)(hb1 + l16) * H
                                         + kf * 32 + quad * 8);
            #pragma unroll
            for (int mf = 0; mf < 4; ++mf)
                ha[mf] = __builtin_amdgcn_mfma_f32_16x16x32_bf16(af[mf], bb, ha[mf], 0, 0, 0);
        }
        #pragma unroll
        for (int mf = 0; mf < 4; ++mf)
            #pragma unroll
            for (int r = 0; r < 4; ++r) {
                int mg = mbase + mf * 16 + quad * 4 + r;
                int ng = hb1 + l16;
                float v = ha[mf][r] + bh;
                p.hid[(size_t)mg * 512 + ng] = (bf16_t)fmaxf(v, 0.0f);
            }
    };

    // ---- heads layer 2 (L0 blocks): group-local rows, 64x22 outputs ----
    auto heads2w = [&](int s) {
        int idx = nt * 256 + tid;          // 0..2047, need 64*22 = 1408
        if (idx >= 64 * 22) return;
        int lr = idx / 22;
        int o  = idx - lr * 22;
        int m  = mbase + lr;
        const bf16_t* hrow = p.hid + (size_t)m * 512;
        const float* wp; float bias; int k0, len;
        if (o < 4)      { wp = p.cw2 + o * 128;       bias = p.cb2[o];     k0 = 0;   len = 128; }
        else if (o < 6) { wp = p.sw2 + (o - 4) * 128; bias = p.sb2[o - 4]; k0 = 128; len = 128; }
        else            { wp = p.lw2 + (o - 6) * 256; bias = p.lb2[o - 6]; k0 = 256; len = 256; }
        float acc = bias;
        for (int k = 0; k < len; k += 4) {
            f32x4 wv = *(const f32x4*)(wp + k);
            acc += (float)hrow[k0 + k]     * wv.x;
            acc += (float)hrow[k0 + k + 1] * wv.y;
            acc += (float)hrow[k0 + k + 2] * wv.z;
            acc += (float)hrow[k0 + k + 3] * wv.w;
        }
        int b = m / NN, n = m - b * NN;
        p.out[(((size_t)b * STEPS + s) * NN + n) * 22 + o] = acc;
    };

    // ---- layernorm: group-local, 16 blocks x 4 samples (1/wave) ----
    auto lnw = [&](const bf16_t* src) {
        int sample = mbase + bg * 4 + w;
        const bf16_t* rw2 = src + (size_t)sample * H;
        float v[4];
        #pragma unroll
        for (int j = 0; j < 4; ++j) v[j] = (float)rw2[lane * 4 + j];
        float sm = v[0] + v[1] + v[2] + v[3];
        #pragma unroll
        for (int off = 32; off > 0; off >>= 1) sm += __shfl_xor(sm, off);
        float mean = sm * (1.0f / H);
        float q = 0.f;
        #pragma unroll
        for (int j = 0; j < 4; ++j) { float d = v[j] - mean; q += d * d; }
        #pragma unroll
        for (int off = 32; off > 0; off >>= 1) q += __shfl_xor(q, off);
        float rstd = rsqrtf(q * (1.0f / H) + 1e-5f);
        #pragma unroll
        for (int j = 0; j < 4; ++j)
            p.ht[(size_t)sample * H + lane * 4 + j] =
                (bf16_t)((v[j] - mean) * rstd * lgv[j] + lbv[j]);
    };

    // ======== encoder: 65 pipelined rounds (L0 step r || L1 step r-1) ========
    #pragma unroll 1
    for (int r = 0; r < 65; ++r) {
        if (isL0) {
            if (r < 64)
                cellw(p.xb + (size_t)r * 25600, xoffq, h0buf[(r + 1) & 1],
                      h0buf[r & 1]);
        } else {
            if (r >= 1)
                cellw(h0buf[(r + 1) & 1], hoffq, h1buf[r & 1], h1buf[(r + 1) & 1]);
        }
        bar();
    }
    // h0(63) in h0buf[1], h1(63) in h1buf[1]
    lnw(h1buf[1]);
    bar();

    // ======== decoder: 10 steps ========
    #pragma unroll 1
    for (int s = 0; s < STEPS; ++s) {
        if (isL0) cellw(p.ht, hoffq, h0buf[(s + 1) & 1], h0buf[s & 1]);
        else      heads1w();
        bar();
        if (!isL0) cellw(h0buf[s & 1], hoffq, h1buf[(s + 1) & 1], h1buf[s & 1]);
        else       heads2w(s);
        bar();
        if (s < STEPS - 1) { lnw(h1buf[s & 1]); bar(); }
    }
}

// ===========================================================================
// Fallback path (multi-launch, used only if cooperative launch fails)
// ===========================================================================
__global__ __launch_bounds__(256)
void cell_kernel(const float* __restrict__ xsrc, int t,
                 const bf16_t* __restrict__ a1,
                 const bf16_t* __restrict__ a2,
                 const bf16_t* __restrict__ Wc,
                 const float* __restrict__ biasr,
                 float* __restrict__ cst,
                 bf16_t* __restrict__ hout)
{
    __shared__ char smem_raw[18432];
    bf16_t* As = (bf16_t*)smem_raw;
    bf16_t* Bs = (bf16_t*)(smem_raw + 9216);
    float*  Gsf = (float*)smem_raw;

    const int tid  = threadIdx.x;
    const int mblk = blockIdx.x;
    const int nblk = blockIdx.y;
    const int am = tid >> 2;
    const int kc = (tid & 3) << 4;
    const int gm = mblk * 64 + am;

    const float*  xrow  = nullptr;
    const bf16_t* arow1 = nullptr;
    if (xsrc) {
        int b = gm / NN;
        int n = gm - b * NN;
        xrow = xsrc + (((size_t)b * SS + t) * NN + n) * H;
    } else {
        arow1 = a1 + (size_t)gm * H;
    }
    const bf16_t* arow2 = a2 + (size_t)gm * H;
    const bf16_t* brow  = Wc + (size_t)(nblk * 64 + am) * KD;

    bf16x8 ra0, ra1, rb0, rb1;
    auto loadA = [&](int ko) {
        int k = ko + kc;
        if (xsrc) {
            if (k < 256) {
                const f32x4* pq = (const f32x4*)(xrow + k);
                f32x4 f0 = pq[0], f1 = pq[1], f2 = pq[2], f3 = pq[3];
                bf16x8 v0, v1;
                v0[0]=(bf16_t)f0.x; v0[1]=(bf16_t)f0.y; v0[2]=(bf16_t)f0.z; v0[3]=(bf16_t)f0.w;
                v0[4]=(bf16_t)f1.x; v0[5]=(bf16_t)f1.y; v0[6]=(bf16_t)f1.z; v0[7]=(bf16_t)f1.w;
                v1[0]=(bf16_t)f2.x; v1[1]=(bf16_t)f2.y; v1[2]=(bf16_t)f2.z; v1[3]=(bf16_t)f2.w;
                v1[4]=(bf16_t)f3.x; v1[5]=(bf16_t)f3.y; v1[6]=(bf16_t)f3.z; v1[7]=(bf16_t)f3.w;
                ra0 = v0; ra1 = v1;
            } else {
                const bf16x8* pq = (const bf16x8*)(arow2 + (k - 256));
                ra0 = pq[0]; ra1 = pq[1];
            }
        } else {
            const bf16x8* pq = (k < 256) ? (const bf16x8*)(arow1 + k)
                                         : (const bf16x8*)(arow2 + (k - 256));
            ra0 = pq[0]; ra1 = pq[1];
        }
    };
    auto loadB = [&](int ko) {
        const bf16x8* pq = (const bf16x8*)(brow + ko + kc);
        rb0 = pq[0]; rb1 = pq[1];
    };
    loadA(0); loadB(0);

    const int w    = tid >> 6;
    const int lane = tid & 63;
    const int wm   = w & 1, wn = w >> 1;
    const int quad = lane >> 4, l16 = lane & 15;

    f32x4 zero4 = {0.f, 0.f, 0.f, 0.f};
    f32x4 acc[2][2] = {{zero4, zero4}, {zero4, zero4}};

    for (int kk = 0; kk < 8; ++kk) {
        __syncthreads();
        *(bf16x8*)(As + am * 72 + kc)     = ra0;
        *(bf16x8*)(As + am * 72 + kc + 8) = ra1;
        *(bf16x8*)(Bs + am * 72 + kc)     = rb0;
        *(bf16x8*)(Bs + am * 72 + kc + 8) = rb1;
        __syncthreads();
        if (kk < 7) { loadA((kk + 1) * 64); loadB((kk + 1) * 64); }
        #pragma unroll
        for (int ks = 0; ks < 2; ++ks) {
            bf16x8 af[2], bb[2];
            #pragma unroll
            for (int mi = 0; mi < 2; ++mi)
                af[mi] = *(const bf16x8*)(As + (wm * 32 + mi * 16 + l16) * 72 + ks * 32 + quad * 8);
            #pragma unroll
            for (int ni = 0; ni < 2; ++ni)
                bb[ni] = *(const bf16x8*)(Bs + (wn * 32 + ni * 16 + l16) * 72 + ks * 32 + quad * 8);
            #pragma unroll
            for (int mi = 0; mi < 2; ++mi)
                #pragma unroll
                for (int ni = 0; ni < 2; ++ni)
                    acc[mi][ni] = __builtin_amdgcn_mfma_f32_16x16x32_bf16(
                        af[mi], bb[ni], acc[mi][ni], 0, 0, 0);
        }
    }

    __syncthreads();
    float bvv[2];
    #pragma unroll
    for (int ni = 0; ni < 2; ++ni)
        bvv[ni] = biasr[nblk * 64 + wn * 32 + ni * 16 + l16];

    #pragma unroll
    for (int mi = 0; mi < 2; ++mi)
        #pragma unroll
        for (int ni = 0; ni < 2; ++ni)
            #pragma unroll
            for (int r = 0; r < 4; ++r) {
                int ml = wm * 32 + mi * 16 + quad * 4 + r;
                int nl = wn * 32 + ni * 16 + l16;
                Gsf[ml * 68 + nl] = acc[mi][ni][r] + bvv[ni];
            }
    __syncthreads();

    #pragma unroll
    for (int e = 0; e < 4; ++e) {
        int id = tid + 256 * e;
        int ml = id >> 4;
        int jl = id & 15;
        f32x4 g4 = *(const f32x4*)(Gsf + ml * 68 + jl * 4);
        int gmm = mblk * 64 + ml;
        int jg  = nblk * 16 + jl;
        float co = cst[(size_t)gmm * H + jg];
        float iv = sigm(g4.x);
        float fv = sigm(g4.y);
        float gv = tanh_c(g4.z);
        float ov = sigm(g4.w);
        float cn = fv * co + iv * gv;
        float hn = ov * tanh_c(cn);
        cst[(size_t)gmm * H + jg]  = cn;
        hout[(size_t)gmm * H + jg] = (bf16_t)hn;
    }
}

__global__ __launch_bounds__(256)
void heads1_kernel(const bf16_t* __restrict__ a1,
                   const bf16_t* __restrict__ Wh,
                   const float* __restrict__ biash,
                   bf16_t* __restrict__ hid)
{
    __shared__ char smem_raw[18432];
    bf16_t* As = (bf16_t*)smem_raw;
    bf16_t* Bs = (bf16_t*)(smem_raw + 9216);

    const int tid  = threadIdx.x;
    const int mblk = blockIdx.x;
    const int nblk = blockIdx.y;
    const int am = tid >> 2;
    const int kc = (tid & 3) << 4;
    const int gm = mblk * 64 + am;
    const bf16_t* arow = a1 + (size_t)gm * H;
    const bf16_t* brow = Wh + (size_t)(nblk * 64 + am) * H;

    bf16x8 ra0, ra1, rb0, rb1;
    auto load = [&](int ko) {
        const bf16x8* pa = (const bf16x8*)(arow + ko + kc);
        ra0 = pa[0]; ra1 = pa[1];
        const bf16x8* pb = (const bf16x8*)(brow + ko + kc);
        rb0 = pb[0]; rb1 = pb[1];
    };
    load(0);

    const int w    = tid >> 6;
    const int lane = tid & 63;
    const int wm   = w & 1, wn = w >> 1;
    const int quad = lane >> 4, l16 = lane & 15;

    f32x4 zero4 = {0.f, 0.f, 0.f, 0.f};
    f32x4 acc[2][2] = {{zero4, zero4}, {zero4, zero4}};

    for (int kk = 0; kk < 4; ++kk) {
        __syncthreads();
        *(bf16x8*)(As + am * 72 + kc)     = ra0;
        *(bf16x8*)(As + am * 72 + kc + 8) = ra1;
        *(bf16x8*)(Bs + am * 72 + kc)     = rb0;
        *(bf16x8*)(Bs + am * 72 + kc + 8) = rb1;
        __syncthreads();
        if (kk < 3) load((kk + 1) * 64);
        #pragma unroll
        for (int ks = 0; ks < 2; ++ks) {
            bf16x8 af[2], bb[2];
            #pragma unroll
            for (int mi = 0; mi < 2; ++mi)
                af[mi] = *(const bf16x8*)(As + (wm * 32 + mi * 16 + l16) * 72 + ks * 32 + quad * 8);
            #pragma unroll
            for (int ni = 0; ni < 2; ++ni)
                bb[ni] = *(const bf16x8*)(Bs + (wn * 32 + ni * 16 + l16) * 72 + ks * 32 + quad * 8);
            #pragma unroll
            for (int mi = 0; mi < 2; ++mi)
                #pragma unroll
                for (int ni = 0; ni < 2; ++ni)
                    acc[mi][ni] = __builtin_amdgcn_mfma_f32_16x16x32_bf16(
                        af[mi], bb[ni], acc[mi][ni], 0, 0, 0);
        }
    }

    #pragma unroll
    for (int mi = 0; mi < 2; ++mi)
        #pragma unroll
        for (int ni = 0; ni < 2; ++ni)
            #pragma unroll
            for (int r = 0; r < 4; ++r) {
                int mg = mblk * 64 + wm * 32 + mi * 16 + quad * 4 + r;
                int ng = nblk * 64 + wn * 32 + ni * 16 + l16;
                float v = acc[mi][ni][r] + biash[ng];
                hid[(size_t)mg * 512 + ng] = (bf16_t)fmaxf(v, 0.0f);
            }
}

__global__ __launch_bounds__(256)
void heads2_kernel(const bf16_t* __restrict__ hid,
                   const float* __restrict__ cw2, const float* __restrict__ cb2,
                   const float* __restrict__ sw2, const float* __restrict__ sb2,
                   const float* __restrict__ lw2, const float* __restrict__ lb2,
                   float* __restrict__ out, int s)
{
    int idx = blockIdx.x * 256 + threadIdx.x;
    if (idx >= BNROWS * 22) return;
    int m = idx / 22;
    int o = idx - m * 22;
    const bf16_t* hrow = hid + (size_t)m * 512;
    const float* wp; float bias; int k0, len;
    if (o < 4)      { wp = cw2 + o * 128;       bias = cb2[o];     k0 = 0;   len = 128; }
    else if (o < 6) { wp = sw2 + (o - 4) * 128; bias = sb2[o - 4]; k0 = 128; len = 128; }
    else            { wp = lw2 + (o - 6) * 256; bias = lb2[o - 6]; k0 = 256; len = 256; }
    float acc = bias;
    for (int k = 0; k < len; k += 4) {
        f32x4 wv = *(const f32x4*)(wp + k);
        acc += (float)hrow[k0 + k]     * wv.x;
        acc += (float)hrow[k0 + k + 1] * wv.y;
        acc += (float)hrow[k0 + k + 2] * wv.z;
        acc += (float)hrow[k0 + k + 3] * wv.w;
    }
    int b = m / NN, n = m - b * NN;
    out[(((size_t)b * STEPS + s) * NN + n) * 22 + o] = acc;
}

__global__ __launch_bounds__(256)
void ln_kernel(const bf16_t* __restrict__ hin,
               const float* __restrict__ gam, const float* __restrict__ bet,
               bf16_t* __restrict__ hto)
{
    int w = threadIdx.x >> 6;
    int lane = threadIdx.x & 63;
    int sample = blockIdx.x * 4 + w;
    const bf16_t* row = hin + (size_t)sample * H;
    float v[4];
    #pragma unroll
    for (int j = 0; j < 4; ++j) v[j] = (float)row[lane * 4 + j];
    float sm = v[0] + v[1] + v[2] + v[3];
    #pragma unroll
    for (int off = 32; off > 0; off >>= 1) sm += __shfl_xor(sm, off);
    float mean = sm * (1.0f / H);
    float q = 0.f;
    #pragma unroll
    for (int j = 0; j < 4; ++j) { float d = v[j] - mean; q += d * d; }
    #pragma unroll
    for (int off = 32; off > 0; off >>= 1) q += __shfl_xor(q, off);
    float rstd = rsqrtf(q * (1.0f / H) + 1e-5f);
    #pragma unroll
    for (int j = 0; j < 4; ++j) {
        int idx = lane * 4 + j;
        float o = (v[j] - mean) * rstd * gam[idx] + bet[idx];
        hto[(size_t)sample * H + idx] = (bf16_t)o;
    }
}

// ---------------------------------------------------------------------------
extern "C" void kernel_launch(void* const* d_in, const int* in_sizes, int n_in,
                              void* d_out, int out_size, void* d_ws, size_t ws_size,
                              hipStream_t stream)
{
    const float* x    = (const float*)d_in[0];
    const float* Wih0 = (const float*)d_in[1];
    const float* Whh0 = (const float*)d_in[2];
    const float* bih0 = (const float*)d_in[3];
    const float* bhh0 = (const float*)d_in[4];
    const float* Wih1 = (const float*)d_in[5];
    const float* Whh1 = (const float*)d_in[6];
    const float* bih1 = (const float*)d_in[7];
    const float* bhh1 = (const float*)d_in[8];
    const float* lng  = (const float*)d_in[9];
    const float* lnb  = (const float*)d_in[10];
    const float* cw1  = (const float*)d_in[11];
    const float* cb1  = (const float*)d_in[12];
    const float* cw2  = (const float*)d_in[13];
    const float* cb2  = (const float*)d_in[14];
    const float* sw1  = (const float*)d_in[15];
    const float* sb1  = (const float*)d_in[16];
    const float* sw2  = (const float*)d_in[17];
    const float* sb2  = (const float*)d_in[18];
    const float* lw1  = (const float*)d_in[19];
    const float* lb1  = (const float*)d_in[20];
    const float* lw2  = (const float*)d_in[21];
    const float* lb2  = (const float*)d_in[22];
    float* out = (float*)d_out;

    char* ws = (char*)d_ws;
    if (ws_size < 64000000) return;

    bf16_t* W0c   = (bf16_t*)(ws);             // 1,048,576
    bf16_t* W1c   = (bf16_t*)(ws + 1048576);   // 1,048,576
    bf16_t* Wh1w  = (bf16_t*)(ws + 2097152);   //   262,144
    float*  bias0 = (float*)(ws + 2359296);    //     4,096
    float*  bias1 = (float*)(ws + 2363392);    //     4,096
    float*  biash = (float*)(ws + 2367488);    //     2,048
    char* st = ws + 2369536;
    bf16_t* h0a = (bf16_t*)st;                 //   819,200
    bf16_t* h0b = (bf16_t*)(st + 819200);
    bf16_t* h1a = (bf16_t*)(st + 1638400);
    bf16_t* h1b = (bf16_t*)(st + 2457600);
    float*  c0  = (float*)(st + 3276800);      // 1,638,400 (fallback only)
    float*  c1  = (float*)(st + 4915200);      // 1,638,400 (fallback only)
    bf16_t* ht  = (bf16_t*)(st + 6553600);     //   819,200
    bf16_t* hid = (bf16_t*)(st + 7372800);     // 1,638,400
    unsigned* cnt = (unsigned*)(st + 9011200); //     6,400 (25 x 256B)
    bf16_t* xb  = (bf16_t*)(st + 9017600);     // 52,428,800

    // zero h (+c for fallback) and barrier counters
    hipMemsetAsync(st, 0, 6553600, stream);
    hipMemsetAsync(cnt, 0, 6400, stream);

    prep_kernel<<<4615, 256, 0, stream>>>(Wih0, Whh0, bih0, bhh0,
                                          Wih1, Whh1, bih1, bhh1,
                                          cw1, sw1, lw1, cb1, sb1, lb1,
                                          W0c, W1c, Wh1w, bias0, bias1, biash);
    xconv_kernel<<<25600, 256, 0, stream>>>(x, xb);

    PA pa;
    pa.xb = xb; pa.W0c = W0c; pa.W1c = W1c; pa.Wh1 = Wh1w;
    pa.bias0 = bias0; pa.bias1 = bias1; pa.biash = biash;
    pa.lng = lng; pa.lnb = lnb;
    pa.cw2 = cw2; pa.cb2 = cb2; pa.sw2 = sw2; pa.sb2 = sb2;
    pa.lw2 = lw2; pa.lb2 = lb2;
    pa.h0a = h0a; pa.h0b = h0b; pa.h1a = h1a; pa.h1b = h1b;
    pa.ht = ht; pa.hid = hid; pa.cnt = cnt; pa.out = out;

    void* kargs[] = { &pa };
    hipError_t err = hipLaunchCooperativeKernel((void*)persistent_kernel,
                                                dim3(400), dim3(256),
                                                kargs, 0, stream);
    if (err == hipSuccess) return;

    // -------- fallback: multi-launch path --------
    bf16_t* h0buf[2] = { h0a, h0b };
    bf16_t* h1buf[2] = { h1a, h1b };
    dim3 cg2(25, 16);
    int cur = 0;
    for (int t = 0; t < SS; ++t) {
        cell_kernel<<<cg2, 256, 0, stream>>>(x, t, nullptr, h0buf[cur], W0c, bias0,
                                             c0, h0buf[cur ^ 1]);
        cell_kernel<<<cg2, 256, 0, stream>>>(nullptr, 0, h0buf[cur ^ 1], h1buf[cur],
                                             W1c, bias1, c1, h1buf[cur ^ 1]);
        cur ^= 1;
    }
    ln_kernel<<<400, 256, 0, stream>>>(h1buf[cur], lng, lnb, ht);
    for (int s = 0; s < STEPS; ++s) {
        heads1_kernel<<<dim3(25, 8), 256, 0, stream>>>(ht, Wh1w, biash, hid);
        heads2_kernel<<<138, 256, 0, stream>>>(hid, cw2, cb2, sw2, sb2, lw2, lb2,
                                               out, s);
        cell_kernel<<<cg2, 256, 0, stream>>>(nullptr, 0, ht, h0buf[cur], W0c, bias0,
                                             c0, h0buf[cur ^ 1]);
        cell_kernel<<<cg2, 256, 0, stream>>>(nullptr, 0, h0buf[cur ^ 1], h1buf[cur],
                                             W1c, bias1, c1, h1buf[cur ^ 1]);
        cur ^= 1;
        ln_kernel<<<400, 256, 0, stream>>>(h1buf[cur], lng, lnb, ht);
    }
}

// Round 4
// 1256.952 us; speedup vs baseline: 5.0306x; 3.0809x over previous
//
#include <hip/hip_runtime.h>
#include <hip/hip_bf16.h>
#include <stdint.h>

// TemporalDecoder: 2-layer LSTM (H=256) encoder (S=64) + decoder (10 steps) + heads.
// Persistent kernel, weight-stationary (B tiles in VGPR/AGPR), c-state in regs.
// Cross-block h exchange goes through L3 (sc0 sc1 coherent ops) -> no cache
// flushes; per-group (16-block) counter barriers; A-tiles staged in LDS.

#define H 256
#define SS 64
#define NN 100
#define BNROWS 1600
#define KD 512
#define STEPS 10

typedef __bf16 bf16_t;
typedef __attribute__((ext_vector_type(8))) __bf16 bf16x8;
typedef __attribute__((ext_vector_type(4))) __bf16 bf16x4;
typedef __attribute__((ext_vector_type(4))) float f32x4;
typedef __attribute__((ext_vector_type(4))) unsigned uint4v;

__device__ __forceinline__ float sigm(float x) { return 1.0f / (1.0f + __expf(-x)); }
__device__ __forceinline__ float tanh_c(float x) {
    x = fminf(fmaxf(x, -15.0f), 15.0f);
    float e = __expf(2.0f * x);
    return (e - 1.0f) / (e + 1.0f);
}

// coherent (device coherence point = L3) access helpers
__device__ __forceinline__ unsigned ld_sys(const unsigned* p) {
    return __hip_atomic_load(p, __ATOMIC_RELAXED, __HIP_MEMORY_SCOPE_SYSTEM);
}
__device__ __forceinline__ void st_sys(unsigned* p, unsigned v) {
    __hip_atomic_store(p, v, __ATOMIC_RELAXED, __HIP_MEMORY_SCOPE_SYSTEM);
}
__device__ __forceinline__ uint4v ld16_sys(const void* p) {
    uint4v v;
    asm volatile("global_load_dwordx4 %0, %1, off sc0 sc1"
                 : "=v"(v) : "v"(p) : "memory");
    return v;
}
__device__ __forceinline__ unsigned pack_bf16(float a, float b) {
    bf16_t xa = (bf16_t)a, xb = (bf16_t)b;
    unsigned short ua, ub;
    __builtin_memcpy(&ua, &xa, 2);
    __builtin_memcpy(&ub, &xb, 2);
    return (unsigned)ua | ((unsigned)ub << 16);
}
__device__ __forceinline__ float bf16lo(unsigned u) {
    unsigned v = u << 16; float f; __builtin_memcpy(&f, &v, 4); return f;
}
__device__ __forceinline__ float bf16hi(unsigned u) {
    unsigned v = u & 0xffff0000u; float f; __builtin_memcpy(&f, &v, 4); return f;
}
__device__ __forceinline__ float u2f(unsigned u) {
    float f; __builtin_memcpy(&f, &u, 4); return f;
}
__device__ __forceinline__ unsigned f2u(float f) {
    unsigned u; __builtin_memcpy(&u, &f, 4); return u;
}

// ---------------------------------------------------------------------------
// prep: pack weights to bf16. Cell weights: new row nr = 4*j + gate, cols
// [W_ih | W_hh] (K=512). bias = b_ih + b_hh. Head layer-1 stacked 512x256.
// ---------------------------------------------------------------------------
__global__ __launch_bounds__(256)
void prep_kernel(const float* __restrict__ Wih0, const float* __restrict__ Whh0,
                 const float* __restrict__ bih0, const float* __restrict__ bhh0,
                 const float* __restrict__ Wih1, const float* __restrict__ Whh1,
                 const float* __restrict__ bih1, const float* __restrict__ bhh1,
                 const float* __restrict__ cw1, const float* __restrict__ sw1,
                 const float* __restrict__ lw1,
                 const float* __restrict__ cb1, const float* __restrict__ sb1,
                 const float* __restrict__ lb1,
                 bf16_t* __restrict__ W0c, bf16_t* __restrict__ W1c,
                 bf16_t* __restrict__ Wh1, float* __restrict__ bias0,
                 float* __restrict__ bias1, float* __restrict__ biash)
{
    int idx = blockIdx.x * 256 + threadIdx.x;
    if (idx < 524288) {
        int nr = idx >> 9, k = idx & 511;
        int j = nr >> 2, gi = nr & 3;
        int go = gi * 256 + j;
        float v = (k < 256) ? Wih0[go * 256 + k] : Whh0[go * 256 + (k - 256)];
        W0c[idx] = (bf16_t)v;
        return;
    }
    idx -= 524288;
    if (idx < 524288) {
        int nr = idx >> 9, k = idx & 511;
        int j = nr >> 2, gi = nr & 3;
        int go = gi * 256 + j;
        float v = (k < 256) ? Wih1[go * 256 + k] : Whh1[go * 256 + (k - 256)];
        W1c[idx] = (bf16_t)v;
        return;
    }
    idx -= 524288;
    if (idx < 131072) {
        int r = idx >> 8, k = idx & 255;
        float v = (r < 128) ? cw1[r * 256 + k]
                            : (r < 256 ? sw1[(r - 128) * 256 + k]
                                       : lw1[(r - 256) * 256 + k]);
        Wh1[idx] = (bf16_t)v;
        return;
    }
    idx -= 131072;
    if (idx < 1024) {
        int j = idx >> 2, gi = idx & 3, go = gi * 256 + j;
        bias0[idx] = bih0[go] + bhh0[go];
        return;
    }
    idx -= 1024;
    if (idx < 1024) {
        int j = idx >> 2, gi = idx & 3, go = gi * 256 + j;
        bias1[idx] = bih1[go] + bhh1[go];
        return;
    }
    idx -= 1024;
    if (idx < 512) {
        biash[idx] = (idx < 128) ? cb1[idx]
                                 : (idx < 256 ? sb1[idx - 128] : lb1[idx - 256]);
    }
}

// x fp32 [b][s][n][h] -> bf16 [s][m][h]  (m = b*100+n), 26,214,400 elements.
__global__ __launch_bounds__(256)
void xconv_kernel(const float* __restrict__ x, bf16_t* __restrict__ xb)
{
    int o = (blockIdx.x * 256 + threadIdx.x) * 4;   // output element idx
    int s = o / 409600;
    int rem = o - s * 409600;
    int m = rem >> 8;
    int h = rem & 255;
    int b = m / 100, n = m - b * 100;
    const float* src = x + (((size_t)(b * 64 + s) * 100 + n) << 8) + h;
    f32x4 v = *(const f32x4*)src;
    bf16x4 ov;
    ov[0] = (bf16_t)v.x; ov[1] = (bf16_t)v.y; ov[2] = (bf16_t)v.z; ov[3] = (bf16_t)v.w;
    *(bf16x4*)(xb + o) = ov;
}

// ---------------------------------------------------------------------------
// Persistent kernel. 400 blocks x 256 threads (2/CU). Group mt in [0,25):
// blocks {L0(mt,nt=0..7), L1(mt,nt=0..7)} own rows [mt*64, mt*64+64).
// Per-group 16-block barrier (system-scope relaxed atomics at L3, no fences).
// A-tile (64x512) staged in LDS via sc0sc1 dwordx4; B tile resident in regs.
// ---------------------------------------------------------------------------
struct PA {
    const bf16_t* xb;
    const bf16_t* W0c; const bf16_t* W1c; const bf16_t* Wh1;
    const float* bias0; const float* bias1; const float* biash;
    const float* lng; const float* lnb;
    const float* cw2; const float* cb2;
    const float* sw2; const float* sb2;
    const float* lw2; const float* lb2;
    bf16_t* h0a; bf16_t* h0b; bf16_t* h1a; bf16_t* h1b;
    bf16_t* ht; float* hid;
    unsigned* cnt;          // 25 groups x 64 uints (256 B stride)
    float* out;
};

__global__ __launch_bounds__(256, 2)
void persistent_kernel(PA p)
{
    __shared__ uint4v smem[4160];      // 66,560 B: A-stage 64x520 bf16 (Gs overlay)

    const int tid  = threadIdx.x;
    const int w    = tid >> 6;
    const int lane = tid & 63;
    const int quad = lane >> 4;
    const int l16  = lane & 15;
    const bool isL0 = (blockIdx.x < 200);
    const int cb   = isL0 ? (int)blockIdx.x : (int)blockIdx.x - 200;
    const int mt   = cb >> 3;
    const int nt   = cb & 7;
    const int bg   = nt + (isL0 ? 0 : 8);
    const int mbase = mt * 64;
    const int nbase = nt * 128 + w * 32;
    const int hcb   = nbase >> 2;          // h-col base (8 cols per wave)
    float* Gw = (float*)smem + w * 2304;   // wave-private 64x36 f32 overlay

    // staging geometry: thread stages rows {trow + 4i}, cols [tcol8, tcol8+8)
    const int trow  = tid >> 6;
    const int tcol8 = (tid & 63) * 8;
    const bool firsthalf = (tcol8 < 256);
    const int coladj = firsthalf ? tcol8 : tcol8 - 256;
    const size_t stagebyte = ((size_t)(mbase + trow) * 256 + coladj) * 2;

    unsigned* cntg = p.cnt + mt * 64;
    unsigned rnd = 0;
    auto bar = [&]() {
        ++rnd;
        asm volatile("s_waitcnt vmcnt(0) lgkmcnt(0)" ::: "memory");
        __syncthreads();
        if (tid == 0) {
            __hip_atomic_fetch_add(cntg, 1u, __ATOMIC_RELAXED,
                                   __HIP_MEMORY_SCOPE_SYSTEM);
            while (__hip_atomic_load(cntg, __ATOMIC_RELAXED,
                                     __HIP_MEMORY_SCOPE_SYSTEM) < 16u * rnd) { }
        }
        __syncthreads();
    };

    bf16_t* h0buf[2] = { p.h0a, p.h0b };
    bf16_t* h1buf[2] = { p.h1a, p.h1b };

    float bv[2];
    {
        const float* br = isL0 ? p.bias0 : p.bias1;
        #pragma unroll
        for (int nf = 0; nf < 2; ++nf) bv[nf] = br[nbase + nf * 16 + l16];
    }
    const int hb1 = nt * 64 + w * 16;
    const float bh = p.biash[hb1 + l16];
    float lgv[4], lbv[4];
    #pragma unroll
    for (int j = 0; j < 4; ++j) { lgv[j] = p.lng[lane * 4 + j]; lbv[j] = p.lnb[lane * 4 + j]; }

    // resident B tile: 2 nf x 16 kf bf16x8 = 128 regs
    const bf16_t* Wc = isL0 ? p.W0c : p.W1c;
    bf16x8 Breg[2][16];
    #pragma unroll
    for (int nf = 0; nf < 2; ++nf)
        #pragma unroll
        for (int kf = 0; kf < 16; ++kf)
            Breg[nf][kf] = *(const bf16x8*)(Wc + (size_t)(nbase + nf * 16 + l16) * KD
                                            + kf * 32 + quad * 8);

    // c-state: wave-exclusive. index e (0..3) x pair: ml = e*16 + (lane>>2),
    // cols jl2 = (lane&3)*2 .. +1
    float creg[8];
    #pragma unroll
    for (int e = 0; e < 8; ++e) creg[e] = 0.0f;

    // ---- one LSTM cell step for this block/wave ----
    auto cellw = [&](const bf16_t* sA, const bf16_t* sB, bf16_t* hd) {
        // stage 64x512 A-tile into LDS (coherent, two batches of 8x16B)
        {
            const char* sp = (const char*)(firsthalf ? sA : sB) + stagebyte;
            uint4v c[8];
            #pragma unroll
            for (int i = 0; i < 8; ++i) c[i] = ld16_sys(sp + (size_t)i * 2048);
            asm volatile("s_waitcnt vmcnt(0)" ::: "memory");
            #pragma unroll
            for (int i = 0; i < 8; ++i)
                *(uint4v*)((char*)smem + (size_t)(trow + i * 4) * 1040 + tcol8 * 2) = c[i];
            #pragma unroll
            for (int i = 0; i < 8; ++i) c[i] = ld16_sys(sp + (size_t)(i + 8) * 2048);
            asm volatile("s_waitcnt vmcnt(0)" ::: "memory");
            #pragma unroll
            for (int i = 0; i < 8; ++i)
                *(uint4v*)((char*)smem + (size_t)(trow + (i + 8) * 4) * 1040 + tcol8 * 2) = c[i];
        }
        __syncthreads();

        f32x4 zero4 = {0.f, 0.f, 0.f, 0.f};
        f32x4 acc[4][2];
        #pragma unroll
        for (int mf = 0; mf < 4; ++mf)
            #pragma unroll
            for (int nf = 0; nf < 2; ++nf) acc[mf][nf] = zero4;

        #pragma unroll
        for (int kf = 0; kf < 16; ++kf) {
            bf16x8 af[4];
            #pragma unroll
            for (int mf = 0; mf < 4; ++mf)
                af[mf] = *(const bf16x8*)((char*)smem
                            + (size_t)(mf * 16 + l16) * 1040 + kf * 64 + quad * 16);
            #pragma unroll
            for (int mf = 0; mf < 4; ++mf)
                #pragma unroll
                for (int nf = 0; nf < 2; ++nf)
                    acc[mf][nf] = __builtin_amdgcn_mfma_f32_16x16x32_bf16(
                        af[mf], Breg[nf][kf], acc[mf][nf], 0, 0, 0);
        }
        __syncthreads();   // all waves done reading A before Gs overlay

        #pragma unroll
        for (int mf = 0; mf < 4; ++mf)
            #pragma unroll
            for (int nf = 0; nf < 2; ++nf)
                #pragma unroll
                for (int r = 0; r < 4; ++r)
                    Gw[(mf * 16 + quad * 4 + r) * 36 + nf * 16 + l16] =
                        acc[mf][nf][r] + bv[nf];
        asm volatile("s_waitcnt lgkmcnt(0)" ::: "memory");

        // cell update: 4 e x 2 cols per lane; h stored as packed dwords via L3
        #pragma unroll
        for (int e = 0; e < 4; ++e) {
            int ml  = e * 16 + (lane >> 2);
            int jl2 = (lane & 3) * 2;
            f32x4 ga = *(const f32x4*)(Gw + ml * 36 + jl2 * 4);
            f32x4 gb = *(const f32x4*)(Gw + ml * 36 + jl2 * 4 + 4);
            float cn0 = sigm(ga.y) * creg[e * 2] + sigm(ga.x) * tanh_c(ga.z);
            float cn1 = sigm(gb.y) * creg[e * 2 + 1] + sigm(gb.x) * tanh_c(gb.z);
            creg[e * 2]     = cn0;
            creg[e * 2 + 1] = cn1;
            float hn0 = sigm(ga.w) * tanh_c(cn0);
            float hn1 = sigm(gb.w) * tanh_c(cn1);
            st_sys((unsigned*)(hd + (size_t)(mbase + ml) * H + hcb + jl2),
                   pack_bf16(hn0, hn1));
        }
    };

    // ---- heads layer 1 (L1 blocks): hid = relu(ht @ Wh1^T + bh), fp32 out ----
    auto heads1w = [&]() {
        {
            const int hrow0 = tid >> 5;          // 0..7
            const int hcol8 = (tid & 31) * 8;    // 0..248
            const char* sp = (const char*)p.ht
                + ((size_t)(mbase + hrow0) * 256 + hcol8) * 2;
            uint4v c[8];
            #pragma unroll
            for (int i = 0; i < 8; ++i) c[i] = ld16_sys(sp + (size_t)i * 4096);
            asm volatile("s_waitcnt vmcnt(0)" ::: "memory");
            #pragma unroll
            for (int i = 0; i < 8; ++i)
                *(uint4v*)((char*)smem + (size_t)(hrow0 + i * 8) * 1040 + hcol8 * 2) = c[i];
        }
        __syncthreads();

        f32x4 zero4 = {0.f, 0.f, 0.f, 0.f};
        f32x4 ha[4] = {zero4, zero4, zero4, zero4};
        #pragma unroll
        for (int kf = 0; kf < 8; ++kf) {
            bf16x8 bb = *(const bf16x8*)(p.Wh1 + (size_t)(hb1 + l16) * H
                                         + kf * 32 + quad * 8);
            #pragma unroll
            for (int mf = 0; mf < 4; ++mf) {
                bf16x8 af = *(const bf16x8*)((char*)smem
                            + (size_t)(mf * 16 + l16) * 1040 + kf * 64 + quad * 16);
                ha[mf] = __builtin_amdgcn_mfma_f32_16x16x32_bf16(af, bb, ha[mf], 0, 0, 0);
            }
        }
        #pragma unroll
        for (int mf = 0; mf < 4; ++mf)
            #pragma unroll
            for (int r = 0; r < 4; ++r) {
                int mg = mbase + mf * 16 + quad * 4 + r;
                int ng = hb1 + l16;
                float v = fmaxf(ha[mf][r] + bh, 0.0f);
                st_sys((unsigned*)(p.hid + (size_t)mg * 512 + ng), f2u(v));
            }
    };

    // ---- heads layer 2 (L0 blocks): group-local rows, 64x22 outputs ----
    auto heads2w = [&](int s) {
        int idx = nt * 256 + tid;
        if (idx >= 64 * 22) return;
        int lr = idx / 22;
        int o  = idx - lr * 22;
        int m  = mbase + lr;
        const unsigned* hrow = (const unsigned*)(p.hid + (size_t)m * 512);
        const float* wp; float bias; int k0, len;
        if (o < 4)      { wp = p.cw2 + o * 128;       bias = p.cb2[o];     k0 = 0;   len = 128; }
        else if (o < 6) { wp = p.sw2 + (o - 4) * 128; bias = p.sb2[o - 4]; k0 = 128; len = 128; }
        else            { wp = p.lw2 + (o - 6) * 256; bias = p.lb2[o - 6]; k0 = 256; len = 256; }
        float acc = bias;
        for (int k = 0; k < len; k += 4) {
            f32x4 wv = *(const f32x4*)(wp + k);
            acc += u2f(ld_sys(hrow + k0 + k))     * wv.x;
            acc += u2f(ld_sys(hrow + k0 + k + 1)) * wv.y;
            acc += u2f(ld_sys(hrow + k0 + k + 2)) * wv.z;
            acc += u2f(ld_sys(hrow + k0 + k + 3)) * wv.w;
        }
        int b = m / NN, n = m - b * NN;
        p.out[(((size_t)b * STEPS + s) * NN + n) * 22 + o] = acc;
    };

    // ---- layernorm: group-local, 16 blocks x 4 samples (1/wave) ----
    auto lnw = [&](const bf16_t* src) {
        int sample = mbase + bg * 4 + w;
        const unsigned* rp = (const unsigned*)(src + (size_t)sample * H) + lane * 2;
        unsigned u0 = ld_sys(rp), u1 = ld_sys(rp + 1);
        float v[4] = { bf16lo(u0), bf16hi(u0), bf16lo(u1), bf16hi(u1) };
        float sm = v[0] + v[1] + v[2] + v[3];
        #pragma unroll
        for (int off = 32; off > 0; off >>= 1) sm += __shfl_xor(sm, off);
        float mean = sm * (1.0f / H);
        float q = 0.f;
        #pragma unroll
        for (int j = 0; j < 4; ++j) { float d = v[j] - mean; q += d * d; }
        #pragma unroll
        for (int off = 32; off > 0; off >>= 1) q += __shfl_xor(q, off);
        float rstd = rsqrtf(q * (1.0f / H) + 1e-5f);
        float o0 = (v[0] - mean) * rstd * lgv[0] + lbv[0];
        float o1 = (v[1] - mean) * rstd * lgv[1] + lbv[1];
        float o2 = (v[2] - mean) * rstd * lgv[2] + lbv[2];
        float o3 = (v[3] - mean) * rstd * lgv[3] + lbv[3];
        unsigned* wp2 = (unsigned*)(p.ht + (size_t)sample * H) + lane * 2;
        st_sys(wp2,     pack_bf16(o0, o1));
        st_sys(wp2 + 1, pack_bf16(o2, o3));
    };

    // ======== encoder: 65 pipelined rounds (L0 step r || L1 step r-1) ========
    #pragma unroll 1
    for (int r = 0; r < 65; ++r) {
        if (isL0) {
            if (r < 64)
                cellw(p.xb + (size_t)r * 409600, h0buf[(r + 1) & 1], h0buf[r & 1]);
        } else {
            if (r >= 1)
                cellw(h0buf[(r + 1) & 1], h1buf[r & 1], h1buf[(r + 1) & 1]);
        }
        bar();
    }
    lnw(h1buf[1]);
    bar();

    // ======== decoder: 10 steps ========
    #pragma unroll 1
    for (int s = 0; s < STEPS; ++s) {
        if (isL0) cellw(p.ht, h0buf[(s + 1) & 1], h0buf[s & 1]);
        else      heads1w();
        bar();
        if (!isL0) cellw(h0buf[s & 1], h1buf[(s + 1) & 1], h1buf[s & 1]);
        else       heads2w(s);
        bar();
        if (s < STEPS - 1) { lnw(h1buf[s & 1]); bar(); }
    }
}

// ===========================================================================
// Fallback path (multi-launch, used only if cooperative launch fails)
// ===========================================================================
__global__ __launch_bounds__(256)
void cell_kernel(const float* __restrict__ xsrc, int t,
                 const bf16_t* __restrict__ a1,
                 const bf16_t* __restrict__ a2,
                 const bf16_t* __restrict__ Wc,
                 const float* __restrict__ biasr,
                 float* __restrict__ cst,
                 bf16_t* __restrict__ hout)
{
    __shared__ char smem_raw[18432];
    bf16_t* As = (bf16_t*)smem_raw;
    bf16_t* Bs = (bf16_t*)(smem_raw + 9216);
    float*  Gsf = (float*)smem_raw;

    const int tid  = threadIdx.x;
    const int mblk = blockIdx.x;
    const int nblk = blockIdx.y;
    const int am = tid >> 2;
    const int kc = (tid & 3) << 4;
    const int gm = mblk * 64 + am;

    const float*  xrow  = nullptr;
    const bf16_t* arow1 = nullptr;
    if (xsrc) {
        int b = gm / NN;
        int n = gm - b * NN;
        xrow = xsrc + (((size_t)b * SS + t) * NN + n) * H;
    } else {
        arow1 = a1 + (size_t)gm * H;
    }
    const bf16_t* arow2 = a2 + (size_t)gm * H;
    const bf16_t* brow  = Wc + (size_t)(nblk * 64 + am) * KD;

    bf16x8 ra0, ra1, rb0, rb1;
    auto loadA = [&](int ko) {
        int k = ko + kc;
        if (xsrc) {
            if (k < 256) {
                const f32x4* pq = (const f32x4*)(xrow + k);
                f32x4 f0 = pq[0], f1 = pq[1], f2 = pq[2], f3 = pq[3];
                bf16x8 v0, v1;
                v0[0]=(bf16_t)f0.x; v0[1]=(bf16_t)f0.y; v0[2]=(bf16_t)f0.z; v0[3]=(bf16_t)f0.w;
                v0[4]=(bf16_t)f1.x; v0[5]=(bf16_t)f1.y; v0[6]=(bf16_t)f1.z; v0[7]=(bf16_t)f1.w;
                v1[0]=(bf16_t)f2.x; v1[1]=(bf16_t)f2.y; v1[2]=(bf16_t)f2.z; v1[3]=(bf16_t)f2.w;
                v1[4]=(bf16_t)f3.x; v1[5]=(bf16_t)f3.y; v1[6]=(bf16_t)f3.z; v1[7]=(bf16_t)f3.w;
                ra0 = v0; ra1 = v1;
            } else {
                const bf16x8* pq = (const bf16x8*)(arow2 + (k - 256));
                ra0 = pq[0]; ra1 = pq[1];
            }
        } else {
            const bf16x8* pq = (k < 256) ? (const bf16x8*)(arow1 + k)
                                         : (const bf16x8*)(arow2 + (k - 256));
            ra0 = pq[0]; ra1 = pq[1];
        }
    };
    auto loadB = [&](int ko) {
        const bf16x8* pq = (const bf16x8*)(brow + ko + kc);
        rb0 = pq[0]; rb1 = pq[1];
    };
    loadA(0); loadB(0);

    const int w    = tid >> 6;
    const int lane = tid & 63;
    const int wm   = w & 1, wn = w >> 1;
    const int quad = lane >> 4, l16 = lane & 15;

    f32x4 zero4 = {0.f, 0.f, 0.f, 0.f};
    f32x4 acc[2][2] = {{zero4, zero4}, {zero4, zero4}};

    for (int kk = 0; kk < 8; ++kk) {
        __syncthreads();
        *(bf16x8*)(As + am * 72 + kc)     = ra0;
        *(bf16x8*)(As + am * 72 + kc + 8) = ra1;
        *(bf16x8*)(Bs + am * 72 + kc)     = rb0;
        *(bf16x8*)(Bs + am * 72 + kc + 8) = rb1;
        __syncthreads();
        if (kk < 7) { loadA((kk + 1) * 64); loadB((kk + 1) * 64); }
        #pragma unroll
        for (int ks = 0; ks < 2; ++ks) {
            bf16x8 af[2], bb[2];
            #pragma unroll
            for (int mi = 0; mi < 2; ++mi)
                af[mi] = *(const bf16x8*)(As + (wm * 32 + mi * 16 + l16) * 72 + ks * 32 + quad * 8);
            #pragma unroll
            for (int ni = 0; ni < 2; ++ni)
                bb[ni] = *(const bf16x8*)(Bs + (wn * 32 + ni * 16 + l16) * 72 + ks * 32 + quad * 8);
            #pragma unroll
            for (int mi = 0; mi < 2; ++mi)
                #pragma unroll
                for (int ni = 0; ni < 2; ++ni)
                    acc[mi][ni] = __builtin_amdgcn_mfma_f32_16x16x32_bf16(
                        af[mi], bb[ni], acc[mi][ni], 0, 0, 0);
        }
    }

    __syncthreads();
    float bvv[2];
    #pragma unroll
    for (int ni = 0; ni < 2; ++ni)
        bvv[ni] = biasr[nblk * 64 + wn * 32 + ni * 16 + l16];

    #pragma unroll
    for (int mi = 0; mi < 2; ++mi)
        #pragma unroll
        for (int ni = 0; ni < 2; ++ni)
            #pragma unroll
            for (int r = 0; r < 4; ++r) {
                int ml = wm * 32 + mi * 16 + quad * 4 + r;
                int nl = wn * 32 + ni * 16 + l16;
                Gsf[ml * 68 + nl] = acc[mi][ni][r] + bvv[ni];
            }
    __syncthreads();

    #pragma unroll
    for (int e = 0; e < 4; ++e) {
        int id = tid + 256 * e;
        int ml = id >> 4;
        int jl = id & 15;
        f32x4 g4 = *(const f32x4*)(Gsf + ml * 68 + jl * 4);
        int gmm = mblk * 64 + ml;
        int jg  = nblk * 16 + jl;
        float co = cst[(size_t)gmm * H + jg];
        float iv = sigm(g4.x);
        float fv = sigm(g4.y);
        float gv = tanh_c(g4.z);
        float ov = sigm(g4.w);
        float cn = fv * co + iv * gv;
        float hn = ov * tanh_c(cn);
        cst[(size_t)gmm * H + jg]  = cn;
        hout[(size_t)gmm * H + jg] = (bf16_t)hn;
    }
}

__global__ __launch_bounds__(256)
void heads1_kernel(const bf16_t* __restrict__ a1,
                   const bf16_t* __restrict__ Wh,
                   const float* __restrict__ biash,
                   bf16_t* __restrict__ hid)
{
    __shared__ char smem_raw[18432];
    bf16_t* As = (bf16_t*)smem_raw;
    bf16_t* Bs = (bf16_t*)(smem_raw + 9216);

    const int tid  = threadIdx.x;
    const int mblk = blockIdx.x;
    const int nblk = blockIdx.y;
    const int am = tid >> 2;
    const int kc = (tid & 3) << 4;
    const int gm = mblk * 64 + am;
    const bf16_t* arow = a1 + (size_t)gm * H;
    const bf16_t* brow = Wh + (size_t)(nblk * 64 + am) * H;

    bf16x8 ra0, ra1, rb0, rb1;
    auto load = [&](int ko) {
        const bf16x8* pa = (const bf16x8*)(arow + ko + kc);
        ra0 = pa[0]; ra1 = pa[1];
        const bf16x8* pb = (const bf16x8*)(brow + ko + kc);
        rb0 = pb[0]; rb1 = pb[1];
    };
    load(0);

    const int w    = tid >> 6;
    const int lane = tid & 63;
    const int wm   = w & 1, wn = w >> 1;
    const int quad = lane >> 4, l16 = lane & 15;

    f32x4 zero4 = {0.f, 0.f, 0.f, 0.f};
    f32x4 acc[2][2] = {{zero4, zero4}, {zero4, zero4}};

    for (int kk = 0; kk < 4; ++kk) {
        __syncthreads();
        *(bf16x8*)(As + am * 72 + kc)     = ra0;
        *(bf16x8*)(As + am * 72 + kc + 8) = ra1;
        *(bf16x8*)(Bs + am * 72 + kc)     = rb0;
        *(bf16x8*)(Bs + am * 72 + kc + 8) = rb1;
        __syncthreads();
        if (kk < 3) load((kk + 1) * 64);
        #pragma unroll
        for (int ks = 0; ks < 2; ++ks) {
            bf16x8 af[2], bb[2];
            #pragma unroll
            for (int mi = 0; mi < 2; ++mi)
                af[mi] = *(const bf16x8*)(As + (wm * 32 + mi * 16 + l16) * 72 + ks * 32 + quad * 8);
            #pragma unroll
            for (int ni = 0; ni < 2; ++ni)
                bb[ni] = *(const bf16x8*)(Bs + (wn * 32 + ni * 16 + l16) * 72 + ks * 32 + quad * 8);
            #pragma unroll
            for (int mi = 0; mi < 2; ++mi)
                #pragma unroll
                for (int ni = 0; ni < 2; ++ni)
                    acc[mi][ni] = __builtin_amdgcn_mfma_f32_16x16x32_bf16(
                        af[mi], bb[ni], acc[mi][ni], 0, 0, 0);
        }
    }

    #pragma unroll
    for (int mi = 0; mi < 2; ++mi)
        #pragma unroll
        for (int ni = 0; ni < 2; ++ni)
            #pragma unroll
            for (int r = 0; r < 4; ++r) {
                int mg = mblk * 64 + wm * 32 + mi * 16 + quad * 4 + r;
                int ng = nblk * 64 + wn * 32 + ni * 16 + l16;
                float v = acc[mi][ni][r] + biash[ng];
                hid[(size_t)mg * 512 + ng] = (bf16_t)fmaxf(v, 0.0f);
            }
}

__global__ __launch_bounds__(256)
void heads2_kernel(const bf16_t* __restrict__ hid,
                   const float* __restrict__ cw2, const float* __restrict__ cb2,
                   const float* __restrict__ sw2, const float* __restrict__ sb2,
                   const float* __restrict__ lw2, const float* __restrict__ lb2,
                   float* __restrict__ out, int s)
{
    int idx = blockIdx.x * 256 + threadIdx.x;
    if (idx >= BNROWS * 22) return;
    int m = idx / 22;
    int o = idx - m * 22;
    const bf16_t* hrow = hid + (size_t)m * 512;
    const float* wp; float bias; int k0, len;
    if (o < 4)      { wp = cw2 + o * 128;       bias = cb2[o];     k0 = 0;   len = 128; }
    else if (o < 6) { wp = sw2 + (o - 4) * 128; bias = sb2[o - 4]; k0 = 128; len = 128; }
    else            { wp = lw2 + (o - 6) * 256; bias = lb2[o - 6]; k0 = 256; len = 256; }
    float acc = bias;
    for (int k = 0; k < len; k += 4) {
        f32x4 wv = *(const f32x4*)(wp + k);
        acc += (float)hrow[k0 + k]     * wv.x;
        acc += (float)hrow[k0 + k + 1] * wv.y;
        acc += (float)hrow[k0 + k + 2] * wv.z;
        acc += (float)hrow[k0 + k + 3] * wv.w;
    }
    int b = m / NN, n = m - b * NN;
    out[(((size_t)b * STEPS + s) * NN + n) * 22 + o] = acc;
}

__global__ __launch_bounds__(256)
void ln_kernel(const bf16_t* __restrict__ hin,
               const float* __restrict__ gam, const float* __restrict__ bet,
               bf16_t* __restrict__ hto)
{
    int w = threadIdx.x >> 6;
    int lane = threadIdx.x & 63;
    int sample = blockIdx.x * 4 + w;
    const bf16_t* row = hin + (size_t)sample * H;
    float v[4];
    #pragma unroll
    for (int j = 0; j < 4; ++j) v[j] = (float)row[lane * 4 + j];
    float sm = v[0] + v[1] + v[2] + v[3];
    #pragma unroll
    for (int off = 32; off > 0; off >>= 1) sm += __shfl_xor(sm, off);
    float mean = sm * (1.0f / H);
    float q = 0.f;
    #pragma unroll
    for (int j = 0; j < 4; ++j) { float d = v[j] - mean; q += d * d; }
    #pragma unroll
    for (int off = 32; off > 0; off >>= 1) q += __shfl_xor(q, off);
    float rstd = rsqrtf(q * (1.0f / H) + 1e-5f);
    #pragma unroll
    for (int j = 0; j < 4; ++j) {
        int idx = lane * 4 + j;
        float o = (v[j] - mean) * rstd * gam[idx] + bet[idx];
        hto[(size_t)sample * H + idx] = (bf16_t)o;
    }
}

// ---------------------------------------------------------------------------
extern "C" void kernel_launch(void* const* d_in, const int* in_sizes, int n_in,
                              void* d_out, int out_size, void* d_ws, size_t ws_size,
                              hipStream_t stream)
{
    const float* x    = (const float*)d_in[0];
    const float* Wih0 = (const float*)d_in[1];
    const float* Whh0 = (const float*)d_in[2];
    const float* bih0 = (const float*)d_in[3];
    const float* bhh0 = (const float*)d_in[4];
    const float* Wih1 = (const float*)d_in[5];
    const float* Whh1 = (const float*)d_in[6];
    const float* bih1 = (const float*)d_in[7];
    const float* bhh1 = (const float*)d_in[8];
    const float* lng  = (const float*)d_in[9];
    const float* lnb  = (const float*)d_in[10];
    const float* cw1  = (const float*)d_in[11];
    const float* cb1  = (const float*)d_in[12];
    const float* cw2  = (const float*)d_in[13];
    const float* cb2  = (const float*)d_in[14];
    const float* sw1  = (const float*)d_in[15];
    const float* sb1  = (const float*)d_in[16];
    const float* sw2  = (const float*)d_in[17];
    const float* sb2  = (const float*)d_in[18];
    const float* lw1  = (const float*)d_in[19];
    const float* lb1  = (const float*)d_in[20];
    const float* lw2  = (const float*)d_in[21];
    const float* lb2  = (const float*)d_in[22];
    float* out = (float*)d_out;

    char* ws = (char*)d_ws;
    if (ws_size < 62200000) return;

    bf16_t* W0c   = (bf16_t*)(ws);             // 1,048,576
    bf16_t* W1c   = (bf16_t*)(ws + 1048576);   // 1,048,576
    bf16_t* Wh1w  = (bf16_t*)(ws + 2097152);   //   262,144
    float*  bias0 = (float*)(ws + 2359296);
    float*  bias1 = (float*)(ws + 2363392);
    float*  biash = (float*)(ws + 2367488);
    char* st = ws + 2369536;
    bf16_t* h0a = (bf16_t*)st;                      //   819,200
    bf16_t* h0b = (bf16_t*)(st + 819200);
    bf16_t* h1a = (bf16_t*)(st + 1638400);
    bf16_t* h1b = (bf16_t*)(st + 2457600);
    bf16_t* ht  = (bf16_t*)(st + 3276800);          //   819,200
    float*  hid = (float*)(st + 4096000);           // 3,276,800 (f32)
    unsigned* cnt = (unsigned*)(st + 7372800);      //     6,400
    bf16_t* xb  = (bf16_t*)(st + 7379200);          // 52,428,800
    // fallback-only c buffers alias the xb region (fallback never uses xb)
    float* c0 = (float*)(st + 7379200);
    float* c1 = (float*)(st + 9017600);

    hipMemsetAsync(st, 0, 3276800, stream);   // zero h buffers
    hipMemsetAsync(cnt, 0, 6400, stream);     // zero barrier counters

    prep_kernel<<<4615, 256, 0, stream>>>(Wih0, Whh0, bih0, bhh0,
                                          Wih1, Whh1, bih1, bhh1,
                                          cw1, sw1, lw1, cb1, sb1, lb1,
                                          W0c, W1c, Wh1w, bias0, bias1, biash);
    xconv_kernel<<<25600, 256, 0, stream>>>(x, xb);

    PA pa;
    pa.xb = xb; pa.W0c = W0c; pa.W1c = W1c; pa.Wh1 = Wh1w;
    pa.bias0 = bias0; pa.bias1 = bias1; pa.biash = biash;
    pa.lng = lng; pa.lnb = lnb;
    pa.cw2 = cw2; pa.cb2 = cb2; pa.sw2 = sw2; pa.sb2 = sb2;
    pa.lw2 = lw2; pa.lb2 = lb2;
    pa.h0a = h0a; pa.h0b = h0b; pa.h1a = h1a; pa.h1b = h1b;
    pa.ht = ht; pa.hid = hid; pa.cnt = cnt; pa.out = out;

    void* kargs[] = { &pa };
    hipError_t err = hipLaunchCooperativeKernel((void*)persistent_kernel,
                                                dim3(400), dim3(256),
                                                kargs, 0, stream);
    if (err == hipSuccess) return;

    // -------- fallback: multi-launch path --------
    hipMemsetAsync(c0, 0, 1638400, stream);
    hipMemsetAsync(c1, 0, 1638400, stream);
    bf16_t* hidb = (bf16_t*)hid;
    bf16_t* h0buf[2] = { h0a, h0b };
    bf16_t* h1buf[2] = { h1a, h1b };
    dim3 cg2(25, 16);
    int cur = 0;
    for (int t = 0; t < SS; ++t) {
        cell_kernel<<<cg2, 256, 0, stream>>>(x, t, nullptr, h0buf[cur], W0c, bias0,
                                             c0, h0buf[cur ^ 1]);
        cell_kernel<<<cg2, 256, 0, stream>>>(nullptr, 0, h0buf[cur ^ 1], h1buf[cur],
                                             W1c, bias1, c1, h1buf[cur ^ 1]);
        cur ^= 1;
    }
    ln_kernel<<<400, 256, 0, stream>>>(h1buf[cur], lng, lnb, ht);
    for (int s = 0; s < STEPS; ++s) {
        heads1_kernel<<<dim3(25, 8), 256, 0, stream>>>(ht, Wh1w, biash, hidb);
        heads2_kernel<<<138, 256, 0, stream>>>(hidb, cw2, cb2, sw2, sb2, lw2, lb2,
                                               out, s);
        cell_kernel<<<cg2, 256, 0, stream>>>(nullptr, 0, ht, h0buf[cur], W0c, bias0,
                                             c0, h0buf[cur ^ 1]);
        cell_kernel<<<cg2, 256, 0, stream>>>(nullptr, 0, h0buf[cur ^ 1], h1buf[cur],
                                             W1c, bias1, c1, h1buf[cur ^ 1]);
        cur ^= 1;
        ln_kernel<<<400, 256, 0, stream>>>(h1buf[cur], lng, lnb, ht);
    }
}

// Round 7
// 1101.493 us; speedup vs baseline: 5.7405x; 1.1411x over previous
//
#include <hip/hip_runtime.h>
#include <hip/hip_bf16.h>
#include <stdint.h>

// TemporalDecoder: 2-layer LSTM (H=256) encoder (S=64) + decoder (10 steps) + heads.
// Persistent kernel using round-4's replay-proven inter-block protocol
// (ping-pong h buffers, full 16-block group barrier each phase, memset-zeroed
// sync state, sc0sc1 coherent exchange) + in-block optimizations validated in
// rounds 5/6 first-call: swapped-operand MFMA (gates register-local),
// single-drain staging, store-based (non-RMW) barrier, bf16 hid.

#define H 256
#define SS 64
#define NN 100
#define BNROWS 1600
#define KD 512
#define STEPS 10

typedef __bf16 bf16_t;
typedef __attribute__((ext_vector_type(8))) __bf16 bf16x8;
typedef __attribute__((ext_vector_type(4))) __bf16 bf16x4;
typedef __attribute__((ext_vector_type(4))) float f32x4;
typedef __attribute__((ext_vector_type(4))) unsigned uint4v;

__device__ __forceinline__ float sigm(float x) { return 1.0f / (1.0f + __expf(-x)); }
__device__ __forceinline__ float tanh_c(float x) {
    x = fminf(fmaxf(x, -15.0f), 15.0f);
    float e = __expf(2.0f * x);
    return (e - 1.0f) / (e + 1.0f);
}
__device__ __forceinline__ unsigned pack_bf16(float a, float b) {
    bf16_t xa = (bf16_t)a, xb = (bf16_t)b;
    unsigned short ua, ub;
    __builtin_memcpy(&ua, &xa, 2);
    __builtin_memcpy(&ub, &xb, 2);
    return (unsigned)ua | ((unsigned)ub << 16);
}
__device__ __forceinline__ float bf16lo(unsigned u) {
    unsigned v = u << 16; float f; __builtin_memcpy(&f, &v, 4); return f;
}
__device__ __forceinline__ float bf16hi(unsigned u) {
    unsigned v = u & 0xffff0000u; float f; __builtin_memcpy(&f, &v, 4); return f;
}
// coherent ops: bypass L1/L2, read/write the device coherence point
__device__ __forceinline__ uint4v ld16_sys(const void* p) {
    uint4v v;
    asm volatile("global_load_dwordx4 %0, %1, off sc0 sc1"
                 : "=v"(v) : "v"(p) : "memory");
    return v;
}
__device__ __forceinline__ void st16_sys(void* p, uint4v v) {
    asm volatile("global_store_dwordx4 %0, %1, off sc0 sc1" :: "v"(p), "v"(v) : "memory");
}
__device__ __forceinline__ void st4_sys(void* p, unsigned v) {
    asm volatile("global_store_dword %0, %1, off sc0 sc1" :: "v"(p), "v"(v) : "memory");
}
__device__ __forceinline__ unsigned ld4_sys(const unsigned* p) {
    return __hip_atomic_load(p, __ATOMIC_RELAXED, __HIP_MEMORY_SCOPE_SYSTEM);
}
#define VM_DRAIN() asm volatile("s_waitcnt vmcnt(0)" ::: "memory")

// ---------------------------------------------------------------------------
// prep: pack weights to bf16. Cell weights: new row nr = 4*j + gate, cols
// [W_ih | W_hh] (K=512). bias = b_ih + b_hh. Head layer-1 stacked 512x256.
// ---------------------------------------------------------------------------
__global__ __launch_bounds__(256)
void prep_kernel(const float* __restrict__ Wih0, const float* __restrict__ Whh0,
                 const float* __restrict__ bih0, const float* __restrict__ bhh0,
                 const float* __restrict__ Wih1, const float* __restrict__ Whh1,
                 const float* __restrict__ bih1, const float* __restrict__ bhh1,
                 const float* __restrict__ cw1, const float* __restrict__ sw1,
                 const float* __restrict__ lw1,
                 const float* __restrict__ cb1, const float* __restrict__ sb1,
                 const float* __restrict__ lb1,
                 bf16_t* __restrict__ W0c, bf16_t* __restrict__ W1c,
                 bf16_t* __restrict__ Wh1, float* __restrict__ bias0,
                 float* __restrict__ bias1, float* __restrict__ biash)
{
    int idx = blockIdx.x * 256 + threadIdx.x;
    if (idx < 524288) {
        int nr = idx >> 9, k = idx & 511;
        int j = nr >> 2, gi = nr & 3;
        int go = gi * 256 + j;
        float v = (k < 256) ? Wih0[go * 256 + k] : Whh0[go * 256 + (k - 256)];
        W0c[idx] = (bf16_t)v;
        return;
    }
    idx -= 524288;
    if (idx < 524288) {
        int nr = idx >> 9, k = idx & 511;
        int j = nr >> 2, gi = nr & 3;
        int go = gi * 256 + j;
        float v = (k < 256) ? Wih1[go * 256 + k] : Whh1[go * 256 + (k - 256)];
        W1c[idx] = (bf16_t)v;
        return;
    }
    idx -= 524288;
    if (idx < 131072) {
        int r = idx >> 8, k = idx & 255;
        float v = (r < 128) ? cw1[r * 256 + k]
                            : (r < 256 ? sw1[(r - 128) * 256 + k]
                                       : lw1[(r - 256) * 256 + k]);
        Wh1[idx] = (bf16_t)v;
        return;
    }
    idx -= 131072;
    if (idx < 1024) {
        int j = idx >> 2, gi = idx & 3, go = gi * 256 + j;
        bias0[idx] = bih0[go] + bhh0[go];
        return;
    }
    idx -= 1024;
    if (idx < 1024) {
        int j = idx >> 2, gi = idx & 3, go = gi * 256 + j;
        bias1[idx] = bih1[go] + bhh1[go];
        return;
    }
    idx -= 1024;
    if (idx < 512) {
        biash[idx] = (idx < 128) ? cb1[idx]
                                 : (idx < 256 ? sb1[idx - 128] : lb1[idx - 256]);
    }
}

// x fp32 [b][s][n][h] -> bf16 [s][m][h]  (m = b*100+n)
__global__ __launch_bounds__(256)
void xconv_kernel(const float* __restrict__ x, bf16_t* __restrict__ xb)
{
    int o = (blockIdx.x * 256 + threadIdx.x) * 4;
    int s = o / 409600;
    int rem = o - s * 409600;
    int m = rem >> 8;
    int h = rem & 255;
    int b = m / 100, n = m - b * 100;
    const float* src = x + (((size_t)(b * 64 + s) * 100 + n) << 8) + h;
    f32x4 v = *(const f32x4*)src;
    bf16x4 ov;
    ov[0] = (bf16_t)v.x; ov[1] = (bf16_t)v.y; ov[2] = (bf16_t)v.z; ov[3] = (bf16_t)v.w;
    *(bf16x4*)(xb + o) = ov;
}

// ---------------------------------------------------------------------------
// Persistent kernel. 400 blocks x 256 threads (2/CU). Group grp in [0,25):
// 16 blocks {L0 nt=0..7, L1 nt=0..7} own rows [grp*64, grp*64+64).
// Full group barrier between every phase (round-4 protocol). Wave = 64 rows x
// 32 gate-rows (swapped MFMA: C = W·A^T). B tile resident in 128 VGPRs.
// ---------------------------------------------------------------------------
struct PA {
    const bf16_t* xb;
    const bf16_t* W0c; const bf16_t* W1c; const bf16_t* Wh1;
    const float* bias0; const float* bias1; const float* biash;
    const float* lng; const float* lnb;
    const float* cw2; const float* cb2;
    const float* sw2; const float* sb2;
    const float* lw2; const float* lb2;
    bf16_t* h0a; bf16_t* h0b; bf16_t* h1a; bf16_t* h1b;
    bf16_t* ht; bf16_t* hid;
    unsigned* flags;   // 25 groups x 64 uints (256 B stride), 16 words used
    float* out;
};

__global__ __launch_bounds__(256, 2)
void persistent_kernel(PA p)
{
    __shared__ char stageLDS[66560];   // 64 rows x 1040 B (512 K-cols bf16 + pad)
    __shared__ char tbuf[8192];        // 4 waves x 2 KB output transpose

    const int tid  = threadIdx.x;
    const int w    = tid >> 6;
    const int lane = tid & 63;
    const int quad = lane >> 4;
    const int l16  = lane & 15;
    const bool isL0 = (blockIdx.x < 200);
    const int cb   = isL0 ? (int)blockIdx.x : (int)blockIdx.x - 200;
    const int grp  = cb >> 3;
    const int nt   = cb & 7;
    const int bg   = nt + (isL0 ? 0 : 8);   // group-local block id 0..15
    const int mbase = grp * 64;
    const int nbase = nt * 128 + w * 32;    // gate-row base for this wave
    const int hb    = nt * 64 + w * 16;     // heads1 col base (L1)

    unsigned* fl = p.flags + grp * 64;
    unsigned rnd = 0;
    // full group barrier: parallel flag stores + 64B poll (no RMW)
    auto bar = [&]() {
        ++rnd;
        VM_DRAIN();
        __syncthreads();
        if (tid == 0) {
            st4_sys(fl + bg, rnd);
            for (;;) {
                uint4v a = ld16_sys(fl);
                uint4v b = ld16_sys(fl + 4);
                uint4v c = ld16_sys(fl + 8);
                uint4v d = ld16_sys(fl + 12);
                VM_DRAIN();
                unsigned m = min(min(min(a[0], a[1]), min(a[2], a[3])),
                                 min(min(b[0], b[1]), min(b[2], b[3])));
                m = min(m, min(min(min(c[0], c[1]), min(c[2], c[3])),
                               min(min(d[0], d[1]), min(d[2], d[3]))));
                if (m >= rnd) break;
            }
        }
        __syncthreads();
    };

    bf16_t* h0buf[2] = { p.h0a, p.h0b };
    bf16_t* h1buf[2] = { p.h1a, p.h1b };

    // resident B tile (A-operand role): W rows nbase..nbase+32, K=512
    const bf16_t* Wc = isL0 ? p.W0c : p.W1c;
    bf16x8 Breg[2][16];
    #pragma unroll
    for (int gt = 0; gt < 2; ++gt)
        #pragma unroll
        for (int kf = 0; kf < 16; ++kf)
            Breg[gt][kf] = *(const bf16x8*)(Wc + (size_t)(nbase + gt * 16 + l16) * KD
                                            + kf * 32 + quad * 8);
    const float* br = isL0 ? p.bias0 : p.bias1;
    f32x4 bvq[2];
    bvq[0] = *(const f32x4*)(br + nbase + quad * 4);
    bvq[1] = *(const f32x4*)(br + nbase + 16 + quad * 4);
    f32x4 bhq = *(const f32x4*)(p.biash + hb + quad * 4);
    float lgv[4], lbv[4];
    #pragma unroll
    for (int j = 0; j < 4; ++j) { lgv[j] = p.lng[lane * 4 + j]; lbv[j] = p.lnb[lane * 4 + j]; }

    float creg[8];   // c-state: wave-exclusive, (gt,mt) -> m=mt*16+l16, j=nbase/4+gt*4+quad
    #pragma unroll
    for (int e = 0; e < 8; ++e) creg[e] = 0.0f;

    // ---- stage 64x512 A-tile into LDS (coherent, one vmcnt drain) ----
    auto stage2 = [&](const bf16_t* s1, const bf16_t* s2) {
        const char* sel = (lane < 32) ? (const char*)s1 : ((const char*)s2 - 512);
        const char* gp = sel + (size_t)(mbase + w * 16) * 512 + lane * 16;
        uint4v t[16];
        #pragma unroll
        for (int i = 0; i < 16; ++i) t[i] = ld16_sys(gp + (size_t)i * 512);
        VM_DRAIN();
        char* lp = stageLDS + (w * 16) * 1040 + lane * 16;
        #pragma unroll
        for (int i = 0; i < 16; ++i) *(uint4v*)(lp + i * 1040) = t[i];
        __syncthreads();
    };

    // ---- one LSTM cell step: gates via C = W·A^T (i,f,g,o register-local) ----
    auto cellw = [&](const bf16_t* s1, const bf16_t* s2, bf16_t* hd) {
        stage2(s1, s2);
        f32x4 zero4 = {0.f, 0.f, 0.f, 0.f};
        f32x4 acc[2][4];
        #pragma unroll
        for (int gt = 0; gt < 2; ++gt)
            #pragma unroll
            for (int mt = 0; mt < 4; ++mt) acc[gt][mt] = zero4;
        #pragma unroll
        for (int kf = 0; kf < 16; ++kf) {
            bf16x8 af[4];
            #pragma unroll
            for (int mt = 0; mt < 4; ++mt)
                af[mt] = *(const bf16x8*)(stageLDS + (size_t)(mt * 16 + l16) * 1040
                                          + kf * 64 + quad * 16);
            #pragma unroll
            for (int gt = 0; gt < 2; ++gt)
                #pragma unroll
                for (int mt = 0; mt < 4; ++mt)
                    acc[gt][mt] = __builtin_amdgcn_mfma_f32_16x16x32_bf16(
                        Breg[gt][kf], af[mt], acc[gt][mt], 0, 0, 0);
        }
        bf16_t* tb = (bf16_t*)(tbuf + w * 2048);
        #pragma unroll
        for (int gt = 0; gt < 2; ++gt)
            #pragma unroll
            for (int mt = 0; mt < 4; ++mt) {
                f32x4 g4 = acc[gt][mt] + bvq[gt];          // i,f,g,o
                int ci = gt * 4 + mt;
                float cn = sigm(g4.y) * creg[ci] + sigm(g4.x) * tanh_c(g4.z);
                creg[ci] = cn;
                tb[(mt * 16 + l16) * 8 + gt * 4 + quad] = (bf16_t)(sigm(g4.w) * tanh_c(cn));
            }
        asm volatile("s_waitcnt lgkmcnt(0)" ::: "memory");
        bf16x8 hv = *(const bf16x8*)(tb + lane * 8);
        st16_sys((char*)hd + ((size_t)(mbase + lane) * 256 + nt * 32 + w * 8) * 2,
                 *(uint4v*)&hv);
    };

    // ---- heads layer 1 (L1 blocks): hid = relu(ht @ Wh1^T + b), bf16 out ----
    auto heads1w = [&]() {
        {
            const int hrow0 = tid >> 5;          // 0..7
            const int hcol8 = (tid & 31) * 8;    // 0..248
            const char* gp = (const char*)p.ht
                + ((size_t)(mbase + hrow0) * 256 + hcol8) * 2;
            uint4v t[8];
            #pragma unroll
            for (int i = 0; i < 8; ++i) t[i] = ld16_sys(gp + (size_t)i * 4096);
            VM_DRAIN();
            #pragma unroll
            for (int i = 0; i < 8; ++i)
                *(uint4v*)(stageLDS + (size_t)(hrow0 + i * 8) * 1040 + hcol8 * 2) = t[i];
        }
        __syncthreads();
        f32x4 zero4 = {0.f, 0.f, 0.f, 0.f};
        f32x4 ha[4] = {zero4, zero4, zero4, zero4};
        #pragma unroll
        for (int kf = 0; kf < 8; ++kf) {
            bf16x8 bb = *(const bf16x8*)(p.Wh1 + (size_t)(hb + l16) * 256
                                         + kf * 32 + quad * 8);
            #pragma unroll
            for (int mt = 0; mt < 4; ++mt) {
                bf16x8 af = *(const bf16x8*)(stageLDS + (size_t)(mt * 16 + l16) * 1040
                                             + kf * 64 + quad * 16);
                ha[mt] = __builtin_amdgcn_mfma_f32_16x16x32_bf16(bb, af, ha[mt], 0, 0, 0);
            }
        }
        bf16_t* tb = (bf16_t*)(tbuf + w * 2048);
        #pragma unroll
        for (int mt = 0; mt < 4; ++mt) {
            f32x4 v = ha[mt] + bhq;
            bf16x4 pk;
            #pragma unroll
            for (int r = 0; r < 4; ++r) pk[r] = (bf16_t)fmaxf(v[r], 0.0f);
            *(bf16x4*)(tb + (mt * 16 + l16) * 16 + quad * 4) = pk;
        }
        asm volatile("s_waitcnt lgkmcnt(0)" ::: "memory");
        bf16x8 v0 = *(const bf16x8*)(tb + lane * 16);
        bf16x8 v1 = *(const bf16x8*)(tb + lane * 16 + 8);
        char* dst = (char*)p.hid + ((size_t)(mbase + lane) * 512 + hb) * 2;
        st16_sys(dst, *(uint4v*)&v0);
        st16_sys(dst + 16, *(uint4v*)&v1);
    };

    // ---- heads layer 2 (L0 blocks): group-local rows, coherent hid reads ----
    auto heads2w = [&](int s) {
        int idx = nt * 256 + tid;
        if (idx >= 64 * 22) return;
        int lr = idx / 22;
        int o  = idx - lr * 22;
        int m  = mbase + lr;
        const char* hrow = (const char*)(p.hid + (size_t)m * 512);
        const float* wp; float bias; int k0, len;
        if (o < 4)      { wp = p.cw2 + o * 128;       bias = p.cb2[o];     k0 = 0;   len = 128; }
        else if (o < 6) { wp = p.sw2 + (o - 4) * 128; bias = p.sb2[o - 4]; k0 = 128; len = 128; }
        else            { wp = p.lw2 + (o - 6) * 256; bias = p.lb2[o - 6]; k0 = 256; len = 256; }
        float acc = bias;
        for (int kb = 0; kb < len; kb += 64) {
            uint4v hv[8];
            #pragma unroll
            for (int i = 0; i < 8; ++i)
                hv[i] = ld16_sys(hrow + (size_t)(k0 + kb + i * 8) * 2);
            VM_DRAIN();
            #pragma unroll
            for (int i = 0; i < 8; ++i) {
                bf16x8 h8 = *(bf16x8*)&hv[i];
                const float* wpp = wp + kb + i * 8;
                f32x4 w0 = *(const f32x4*)wpp;
                f32x4 w1 = *(const f32x4*)(wpp + 4);
                acc += (float)h8[0] * w0.x + (float)h8[1] * w0.y
                     + (float)h8[2] * w0.z + (float)h8[3] * w0.w
                     + (float)h8[4] * w1.x + (float)h8[5] * w1.y
                     + (float)h8[6] * w1.z + (float)h8[7] * w1.w;
            }
        }
        int b = m / NN, n = m - b * NN;
        p.out[(((size_t)b * STEPS + s) * NN + n) * 22 + o] = acc;
    };

    // ---- layernorm: group-local, 16 blocks x 4 samples (1/wave) -> ht ----
    auto lnw = [&](const bf16_t* src) {
        int sample = mbase + bg * 4 + w;
        const unsigned* rp = (const unsigned*)(src + (size_t)sample * H) + lane * 2;
        unsigned u0 = ld4_sys(rp), u1 = ld4_sys(rp + 1);
        float v[4] = { bf16lo(u0), bf16hi(u0), bf16lo(u1), bf16hi(u1) };
        float sm = v[0] + v[1] + v[2] + v[3];
        #pragma unroll
        for (int off = 32; off > 0; off >>= 1) sm += __shfl_xor(sm, off);
        float mean = sm * (1.0f / H);
        float q = 0.f;
        #pragma unroll
        for (int j = 0; j < 4; ++j) { float d = v[j] - mean; q += d * d; }
        #pragma unroll
        for (int off = 32; off > 0; off >>= 1) q += __shfl_xor(q, off);
        float rstd = rsqrtf(q * (1.0f / H) + 1e-5f);
        float o0 = (v[0] - mean) * rstd * lgv[0] + lbv[0];
        float o1 = (v[1] - mean) * rstd * lgv[1] + lbv[1];
        float o2 = (v[2] - mean) * rstd * lgv[2] + lbv[2];
        float o3 = (v[3] - mean) * rstd * lgv[3] + lbv[3];
        unsigned* wp2 = (unsigned*)(p.ht + (size_t)sample * H) + lane * 2;
        st4_sys(wp2,     pack_bf16(o0, o1));
        st4_sys(wp2 + 1, pack_bf16(o2, o3));
    };

    // ======== encoder: 65 pipelined rounds (L0 step r || L1 step r-1) ========
    #pragma unroll 1
    for (int r = 0; r < 65; ++r) {
        if (isL0) {
            if (r < 64)
                cellw(p.xb + (size_t)r * 409600, h0buf[(r + 1) & 1], h0buf[r & 1]);
        } else {
            if (r >= 1)
                cellw(h0buf[(r + 1) & 1], h1buf[r & 1], h1buf[(r + 1) & 1]);
        }
        bar();
    }
    lnw(h1buf[1]);   // h1(63) in h1buf[1]
    bar();

    // ======== decoder: 10 steps ========
    #pragma unroll 1
    for (int s = 0; s < STEPS; ++s) {
        if (isL0) cellw(p.ht, h0buf[(s + 1) & 1], h0buf[s & 1]);
        else      heads1w();
        bar();
        if (!isL0) cellw(h0buf[s & 1], h1buf[(s + 1) & 1], h1buf[s & 1]);
        else       heads2w(s);
        bar();
        if (s < STEPS - 1) { lnw(h1buf[s & 1]); bar(); }
    }
}

// ===========================================================================
// Fallback path (multi-launch, used only if cooperative launch fails)
// ===========================================================================
__global__ __launch_bounds__(256)
void cell_kernel(const float* __restrict__ xsrc, int t,
                 const bf16_t* __restrict__ a1,
                 const bf16_t* __restrict__ a2,
                 const bf16_t* __restrict__ Wc,
                 const float* __restrict__ biasr,
                 float* __restrict__ cst,
                 bf16_t* __restrict__ hout)
{
    __shared__ char smem_raw[18432];
    bf16_t* As = (bf16_t*)smem_raw;
    bf16_t* Bs = (bf16_t*)(smem_raw + 9216);
    float*  Gsf = (float*)smem_raw;

    const int tid  = threadIdx.x;
    const int mblk = blockIdx.x;
    const int nblk = blockIdx.y;
    const int am = tid >> 2;
    const int kc = (tid & 3) << 4;
    const int gm = mblk * 64 + am;

    const float*  xrow  = nullptr;
    const bf16_t* arow1 = nullptr;
    if (xsrc) {
        int b = gm / NN;
        int n = gm - b * NN;
        xrow = xsrc + (((size_t)b * SS + t) * NN + n) * H;
    } else {
        arow1 = a1 + (size_t)gm * H;
    }
    const bf16_t* arow2 = a2 + (size_t)gm * H;
    const bf16_t* brow  = Wc + (size_t)(nblk * 64 + am) * KD;

    bf16x8 ra0, ra1, rb0, rb1;
    auto loadA = [&](int ko) {
        int k = ko + kc;
        if (xsrc) {
            if (k < 256) {
                const f32x4* pq = (const f32x4*)(xrow + k);
                f32x4 fq0 = pq[0], fq1 = pq[1], fq2 = pq[2], fq3 = pq[3];
                bf16x8 v0, v1;
                v0[0]=(bf16_t)fq0.x; v0[1]=(bf16_t)fq0.y; v0[2]=(bf16_t)fq0.z; v0[3]=(bf16_t)fq0.w;
                v0[4]=(bf16_t)fq1.x; v0[5]=(bf16_t)fq1.y; v0[6]=(bf16_t)fq1.z; v0[7]=(bf16_t)fq1.w;
                v1[0]=(bf16_t)fq2.x; v1[1]=(bf16_t)fq2.y; v1[2]=(bf16_t)fq2.z; v1[3]=(bf16_t)fq2.w;
                v1[4]=(bf16_t)fq3.x; v1[5]=(bf16_t)fq3.y; v1[6]=(bf16_t)fq3.z; v1[7]=(bf16_t)fq3.w;
                ra0 = v0; ra1 = v1;
            } else {
                const bf16x8* pq = (const bf16x8*)(arow2 + (k - 256));
                ra0 = pq[0]; ra1 = pq[1];
            }
        } else {
            const bf16x8* pq = (k < 256) ? (const bf16x8*)(arow1 + k)
                                         : (const bf16x8*)(arow2 + (k - 256));
            ra0 = pq[0]; ra1 = pq[1];
        }
    };
    auto loadB = [&](int ko) {
        const bf16x8* pq = (const bf16x8*)(brow + ko + kc);
        rb0 = pq[0]; rb1 = pq[1];
    };
    loadA(0); loadB(0);

    const int w    = tid >> 6;
    const int lane = tid & 63;
    const int wm   = w & 1, wn = w >> 1;
    const int quad = lane >> 4, l16 = lane & 15;

    f32x4 zero4 = {0.f, 0.f, 0.f, 0.f};
    f32x4 acc[2][2] = {{zero4, zero4}, {zero4, zero4}};

    for (int kk = 0; kk < 8; ++kk) {
        __syncthreads();
        *(bf16x8*)(As + am * 72 + kc)     = ra0;
        *(bf16x8*)(As + am * 72 + kc + 8) = ra1;
        *(bf16x8*)(Bs + am * 72 + kc)     = rb0;
        *(bf16x8*)(Bs + am * 72 + kc + 8) = rb1;
        __syncthreads();
        if (kk < 7) { loadA((kk + 1) * 64); loadB((kk + 1) * 64); }
        #pragma unroll
        for (int ks = 0; ks < 2; ++ks) {
            bf16x8 af[2], bb[2];
            #pragma unroll
            for (int mi = 0; mi < 2; ++mi)
                af[mi] = *(const bf16x8*)(As + (wm * 32 + mi * 16 + l16) * 72 + ks * 32 + quad * 8);
            #pragma unroll
            for (int ni = 0; ni < 2; ++ni)
                bb[ni] = *(const bf16x8*)(Bs + (wn * 32 + ni * 16 + l16) * 72 + ks * 32 + quad * 8);
            #pragma unroll
            for (int mi = 0; mi < 2; ++mi)
                #pragma unroll
                for (int ni = 0; ni < 2; ++ni)
                    acc[mi][ni] = __builtin_amdgcn_mfma_f32_16x16x32_bf16(
                        af[mi], bb[ni], acc[mi][ni], 0, 0, 0);
        }
    }

    __syncthreads();
    float bvv[2];
    #pragma unroll
    for (int ni = 0; ni < 2; ++ni)
        bvv[ni] = biasr[nblk * 64 + wn * 32 + ni * 16 + l16];

    #pragma unroll
    for (int mi = 0; mi < 2; ++mi)
        #pragma unroll
        for (int ni = 0; ni < 2; ++ni)
            #pragma unroll
            for (int r = 0; r < 4; ++r) {
                int ml = wm * 32 + mi * 16 + quad * 4 + r;
                int nl = wn * 32 + ni * 16 + l16;
                Gsf[ml * 68 + nl] = acc[mi][ni][r] + bvv[ni];
            }
    __syncthreads();

    #pragma unroll
    for (int e = 0; e < 4; ++e) {
        int id = tid + 256 * e;
        int ml = id >> 4;
        int jl = id & 15;
        f32x4 g4 = *(const f32x4*)(Gsf + ml * 68 + jl * 4);
        int gmm = mblk * 64 + ml;
        int jg  = nblk * 16 + jl;
        float co = cst[(size_t)gmm * H + jg];
        float cn = sigm(g4.y) * co + sigm(g4.x) * tanh_c(g4.z);
        cst[(size_t)gmm * H + jg]  = cn;
        hout[(size_t)gmm * H + jg] = (bf16_t)(sigm(g4.w) * tanh_c(cn));
    }
}

__global__ __launch_bounds__(256)
void heads1_kernel(const bf16_t* __restrict__ a1,
                   const bf16_t* __restrict__ Wh,
                   const float* __restrict__ biash,
                   bf16_t* __restrict__ hid)
{
    __shared__ char smem_raw[18432];
    bf16_t* As = (bf16_t*)smem_raw;
    bf16_t* Bs = (bf16_t*)(smem_raw + 9216);

    const int tid  = threadIdx.x;
    const int mblk = blockIdx.x;
    const int nblk = blockIdx.y;
    const int am = tid >> 2;
    const int kc = (tid & 3) << 4;
    const int gm = mblk * 64 + am;
    const bf16_t* arow = a1 + (size_t)gm * H;
    const bf16_t* brow = Wh + (size_t)(nblk * 64 + am) * H;

    bf16x8 ra0, ra1, rb0, rb1;
    auto load = [&](int ko) {
        const bf16x8* pa = (const bf16x8*)(arow + ko + kc);
        ra0 = pa[0]; ra1 = pa[1];
        const bf16x8* pb = (const bf16x8*)(brow + ko + kc);
        rb0 = pb[0]; rb1 = pb[1];
    };
    load(0);

    const int w    = tid >> 6;
    const int lane = tid & 63;
    const int wm   = w & 1, wn = w >> 1;
    const int quad = lane >> 4, l16 = lane & 15;

    f32x4 zero4 = {0.f, 0.f, 0.f, 0.f};
    f32x4 acc[2][2] = {{zero4, zero4}, {zero4, zero4}};

    for (int kk = 0; kk < 4; ++kk) {
        __syncthreads();
        *(bf16x8*)(As + am * 72 + kc)     = ra0;
        *(bf16x8*)(As + am * 72 + kc + 8) = ra1;
        *(bf16x8*)(Bs + am * 72 + kc)     = rb0;
        *(bf16x8*)(Bs + am * 72 + kc + 8) = rb1;
        __syncthreads();
        if (kk < 3) load((kk + 1) * 64);
        #pragma unroll
        for (int ks = 0; ks < 2; ++ks) {
            bf16x8 af[2], bb[2];
            #pragma unroll
            for (int mi = 0; mi < 2; ++mi)
                af[mi] = *(const bf16x8*)(As + (wm * 32 + mi * 16 + l16) * 72 + ks * 32 + quad * 8);
            #pragma unroll
            for (int ni = 0; ni < 2; ++ni)
                bb[ni] = *(const bf16x8*)(Bs + (wn * 32 + ni * 16 + l16) * 72 + ks * 32 + quad * 8);
            #pragma unroll
            for (int mi = 0; mi < 2; ++mi)
                #pragma unroll
                for (int ni = 0; ni < 2; ++ni)
                    acc[mi][ni] = __builtin_amdgcn_mfma_f32_16x16x32_bf16(
                        af[mi], bb[ni], acc[mi][ni], 0, 0, 0);
        }
    }

    #pragma unroll
    for (int mi = 0; mi < 2; ++mi)
        #pragma unroll
        for (int ni = 0; ni < 2; ++ni)
            #pragma unroll
            for (int r = 0; r < 4; ++r) {
                int mg = mblk * 64 + wm * 32 + mi * 16 + quad * 4 + r;
                int ng = nblk * 64 + wn * 32 + ni * 16 + l16;
                float v = acc[mi][ni][r] + biash[ng];
                hid[(size_t)mg * 512 + ng] = (bf16_t)fmaxf(v, 0.0f);
            }
}

__global__ __launch_bounds__(256)
void heads2_kernel(const bf16_t* __restrict__ hid,
                   const float* __restrict__ cw2, const float* __restrict__ cb2,
                   const float* __restrict__ sw2, const float* __restrict__ sb2,
                   const float* __restrict__ lw2, const float* __restrict__ lb2,
                   float* __restrict__ out, int s)
{
    int idx = blockIdx.x * 256 + threadIdx.x;
    if (idx >= BNROWS * 22) return;
    int m = idx / 22;
    int o = idx - m * 22;
    const bf16_t* hrow = hid + (size_t)m * 512;
    const float* wp; float bias; int k0, len;
    if (o < 4)      { wp = cw2 + o * 128;       bias = cb2[o];     k0 = 0;   len = 128; }
    else if (o < 6) { wp = sw2 + (o - 4) * 128; bias = sb2[o - 4]; k0 = 128; len = 128; }
    else            { wp = lw2 + (o - 6) * 256; bias = lb2[o - 6]; k0 = 256; len = 256; }
    float acc = bias;
    for (int k = 0; k < len; k += 4) {
        f32x4 wv = *(const f32x4*)(wp + k);
        acc += (float)hrow[k0 + k]     * wv.x;
        acc += (float)hrow[k0 + k + 1] * wv.y;
        acc += (float)hrow[k0 + k + 2] * wv.z;
        acc += (float)hrow[k0 + k + 3] * wv.w;
    }
    int b = m / NN, n = m - b * NN;
    out[(((size_t)b * STEPS + s) * NN + n) * 22 + o] = acc;
}

__global__ __launch_bounds__(256)
void ln_kernel(const bf16_t* __restrict__ hin,
               const float* __restrict__ gam, const float* __restrict__ bet,
               bf16_t* __restrict__ hto)
{
    int w = threadIdx.x >> 6;
    int lane = threadIdx.x & 63;
    int sample = blockIdx.x * 4 + w;
    const bf16_t* row = hin + (size_t)sample * H;
    float v[4];
    #pragma unroll
    for (int j = 0; j < 4; ++j) v[j] = (float)row[lane * 4 + j];
    float sm = v[0] + v[1] + v[2] + v[3];
    #pragma unroll
    for (int off = 32; off > 0; off >>= 1) sm += __shfl_xor(sm, off);
    float mean = sm * (1.0f / H);
    float q = 0.f;
    #pragma unroll
    for (int j = 0; j < 4; ++j) { float d = v[j] - mean; q += d * d; }
    #pragma unroll
    for (int off = 32; off > 0; off >>= 1) q += __shfl_xor(q, off);
    float rstd = rsqrtf(q * (1.0f / H) + 1e-5f);
    #pragma unroll
    for (int j = 0; j < 4; ++j) {
        int idx = lane * 4 + j;
        float o = (v[j] - mean) * rstd * gam[idx] + bet[idx];
        hto[(size_t)sample * H + idx] = (bf16_t)o;
    }
}

// ---------------------------------------------------------------------------
extern "C" void kernel_launch(void* const* d_in, const int* in_sizes, int n_in,
                              void* d_out, int out_size, void* d_ws, size_t ws_size,
                              hipStream_t stream)
{
    const float* x    = (const float*)d_in[0];
    const float* Wih0 = (const float*)d_in[1];
    const float* Whh0 = (const float*)d_in[2];
    const float* bih0 = (const float*)d_in[3];
    const float* bhh0 = (const float*)d_in[4];
    const float* Wih1 = (const float*)d_in[5];
    const float* Whh1 = (const float*)d_in[6];
    const float* bih1 = (const float*)d_in[7];
    const float* bhh1 = (const float*)d_in[8];
    const float* lng  = (const float*)d_in[9];
    const float* lnb  = (const float*)d_in[10];
    const float* cw1  = (const float*)d_in[11];
    const float* cb1  = (const float*)d_in[12];
    const float* cw2  = (const float*)d_in[13];
    const float* cb2  = (const float*)d_in[14];
    const float* sw1  = (const float*)d_in[15];
    const float* sb1  = (const float*)d_in[16];
    const float* sw2  = (const float*)d_in[17];
    const float* sb2  = (const float*)d_in[18];
    const float* lw1  = (const float*)d_in[19];
    const float* lb1  = (const float*)d_in[20];
    const float* lw2  = (const float*)d_in[21];
    const float* lb2  = (const float*)d_in[22];
    float* out = (float*)d_out;

    char* ws = (char*)d_ws;
    if (ws_size < 65000000) return;

    bf16_t* W0c   = (bf16_t*)(ws);                    // 1,048,576
    bf16_t* W1c   = (bf16_t*)(ws + 1048576);          // 1,048,576
    bf16_t* Wh1w  = (bf16_t*)(ws + 2097152);          //   262,144
    float*  bias0 = (float*)(ws + 2359296);           //     4,096
    float*  bias1 = (float*)(ws + 2363392);           //     4,096
    float*  biash = (float*)(ws + 2367488);           //     2,048
    char* st = ws + 2369536;
    bf16_t* h0a = (bf16_t*)st;                        //   819,200
    bf16_t* h0b = (bf16_t*)(st + 819200);
    bf16_t* h1a = (bf16_t*)(st + 1638400);
    bf16_t* h1b = (bf16_t*)(st + 2457600);
    bf16_t* ht  = (bf16_t*)(st + 3276800);            //   819,200
    bf16_t* hid = (bf16_t*)(st + 4096000);            // 1,638,400 (bf16)
    unsigned* flg = (unsigned*)(st + 5734400);        //     6,400
    bf16_t* xb  = (bf16_t*)(st + 5740800);            // 52,428,800
    // fallback-only c buffers alias xb region (fallback never uses xb)
    float* fc0 = (float*)(st + 5740800);
    float* fc1 = (float*)(st + 7379200);

    hipMemsetAsync(st, 0, 3276800, stream);   // zero h ping-pong buffers
    hipMemsetAsync(flg, 0, 6400, stream);     // zero barrier flags

    prep_kernel<<<4618, 256, 0, stream>>>(Wih0, Whh0, bih0, bhh0,
                                          Wih1, Whh1, bih1, bhh1,
                                          cw1, sw1, lw1, cb1, sb1, lb1,
                                          W0c, W1c, Wh1w, bias0, bias1, biash);
    xconv_kernel<<<25600, 256, 0, stream>>>(x, xb);

    PA pa;
    pa.xb = xb; pa.W0c = W0c; pa.W1c = W1c; pa.Wh1 = Wh1w;
    pa.bias0 = bias0; pa.bias1 = bias1; pa.biash = biash;
    pa.lng = lng; pa.lnb = lnb;
    pa.cw2 = cw2; pa.cb2 = cb2; pa.sw2 = sw2; pa.sb2 = sb2;
    pa.lw2 = lw2; pa.lb2 = lb2;
    pa.h0a = h0a; pa.h0b = h0b; pa.h1a = h1a; pa.h1b = h1b;
    pa.ht = ht; pa.hid = hid; pa.flags = flg; pa.out = out;

    void* kargs[] = { &pa };
    hipError_t err = hipLaunchCooperativeKernel((void*)persistent_kernel,
                                                dim3(400), dim3(256),
                                                kargs, 0, stream);
    if (err == hipSuccess) return;

    // -------- fallback: multi-launch path --------
    hipMemsetAsync(fc0, 0, 1638400, stream);
    hipMemsetAsync(fc1, 0, 1638400, stream);
    bf16_t* h0buf[2] = { h0a, h0b };
    bf16_t* h1buf[2] = { h1a, h1b };
    dim3 cg2(25, 16);
    int cur = 0;
    for (int t = 0; t < SS; ++t) {
        cell_kernel<<<cg2, 256, 0, stream>>>(x, t, nullptr, h0buf[cur], W0c, bias0,
                                             fc0, h0buf[cur ^ 1]);
        cell_kernel<<<cg2, 256, 0, stream>>>(nullptr, 0, h0buf[cur ^ 1], h1buf[cur],
                                             W1c, bias1, fc1, h1buf[cur ^ 1]);
        cur ^= 1;
    }
    ln_kernel<<<400, 256, 0, stream>>>(h1buf[cur], lng, lnb, ht);
    for (int s = 0; s < STEPS; ++s) {
        heads1_kernel<<<dim3(25, 8), 256, 0, stream>>>(ht, Wh1w, biash, hid);
        heads2_kernel<<<138, 256, 0, stream>>>(hid, cw2, cb2, sw2, sb2, lw2, lb2,
                                               out, s);
        cell_kernel<<<cg2, 256, 0, stream>>>(nullptr, 0, ht, h0buf[cur], W0c, bias0,
                                             fc0, h0buf[cur ^ 1]);
        cell_kernel<<<cg2, 256, 0, stream>>>(nullptr, 0, h0buf[cur ^ 1], h1buf[cur],
                                             W1c, bias1, fc1, h1buf[cur ^ 1]);
        cur ^= 1;
        ln_kernel<<<400, 256, 0, stream>>>(h1buf[cur], lng, lnb, ht);
    }
}